// Round 17
// baseline (159.147 us; speedup 1.0000x reference)
//
#include <hip/hip_runtime.h>
#include <math.h>

// ---------------------------------------------------------------------------
// SphericalConvCodec. fp64 decision path (encoder + exact rescore) matches the
// fp64 numpy reference; VQ scan uses f16 MFMA (32x32x16), two barrier-free
// kernels reading the L2-resident codebook straight from global. Round 17:
// identical to round 16 except k_dec launch fixed to 512 threads (round 16
// launched the 8-wave kernel with 256 threads -> k=2,3 never written).
// codebook = d_in[13] (dict-literal order puts it after decoder weights).
// ws layout (byte offsets):
#define WSB_Q64   0u         // 32768*12 double  (3145728 B)
#define WSB_QZ    3145728u   // qmax u32[32768] lives here
#define WSB_KEYS  4718592u   // 32768 u64        (262144 B)
#define WSB_CCH   4980736u   // 8192 double      (65536 B)
#define WSB_W1D   5046272u   // 64 double
#define WSB_W2D   5046784u   // 2048 double [k][o][c]
#define WSB_W3D   5063168u   // 1536 double [q][j][o]
#define WSB_B1D   5075456u   // 16 double
#define WSB_B2D   5075584u   // 32 double
#define WSB_B3D   5075840u   // 12 double
#define WSB_D1R   5075936u   // 1536 float [p][o][c]
#define WSB_D2R   5082080u   // 2048 float [k][o][c]
#define WSB_D3R   5090272u   // 64 float  [k][c]
#define WSB_CB16  5090528u   // 8192*16 _Float16, FRAGMENT-ORDERED [tile][half][col][8]
#define WSB_Q16   5352672u   // 32768*16 _Float16 (1048576 B)
#define DELTA 0.003f
#define SCALE46 70368744177664.0  // 2^46
#define WCAP 512

typedef _Float16 half8 __attribute__((ext_vector_type(8)));
typedef float f32x16 __attribute__((ext_vector_type(16)));

__device__ __forceinline__ float relu(float v) { return v > 0.f ? v : 0.f; }

// monotone float<->uint order transform (valid for all finite floats)
__device__ __forceinline__ unsigned okey(float s) {
  unsigned u = __float_as_uint(s);
  return u ^ ((u & 0x80000000u) ? 0xFFFFFFFFu : 0x80000000u);
}
__device__ __forceinline__ float unokey(unsigned k) {
  unsigned u = k ^ ((k & 0x80000000u) ? 0x80000000u : 0xFFFFFFFFu);
  return __uint_as_float(u);
}

// ---------------------------------------------------------------------------
// prep (grid 32): cchalf fp64; cb16 fragment-ordered; block 0 repacks weights
__global__ __launch_bounds__(256) void k_prep(
    const float* __restrict__ w1, const float* __restrict__ b1,
    const float* __restrict__ w2, const float* __restrict__ b2,
    const float* __restrict__ w3, const float* __restrict__ b3,
    const float* __restrict__ cbk, const float* __restrict__ d1w,
    const float* __restrict__ d2w, const float* __restrict__ d3w,
    double* __restrict__ cch,
    double* __restrict__ w1d, double* __restrict__ w2d,
    double* __restrict__ w3d, double* __restrict__ b1d,
    double* __restrict__ b2d, double* __restrict__ b3d,
    float* __restrict__ d1r, float* __restrict__ d2r,
    float* __restrict__ d3r, _Float16* __restrict__ cb16) {
  int gid = blockIdx.x * 256 + threadIdx.x;  // grid 32 -> 8192
  if (gid < 8192) {
    double s = 0.0;
    half8 lo, hi;
#pragma unroll
    for (int d = 0; d < 12; d++) {
      float cf = cbk[gid * 12 + d];
      double c = (double)cf;
      s = fma(c, c, s);
      if (d < 8) lo[d] = (_Float16)cf; else hi[d - 8] = (_Float16)cf;
    }
#pragma unroll
    for (int d = 4; d < 8; d++) hi[d] = (_Float16)0.f;
    cch[gid] = 0.5 * s;
    // fragment order: tile = code>>5, col = code&31; half k-slice contiguous
    int tile = gid >> 5, col = gid & 31;
    *(half8*)(cb16 + (size_t)(tile * 64 + col) * 8) = lo;        // half 0
    *(half8*)(cb16 + (size_t)(tile * 64 + 32 + col) * 8) = hi;   // half 1
  }
  if (blockIdx.x == 0) {
    int t = threadIdx.x;
    for (int i = t; i < 64; i += 256) w1d[i] = (double)w1[i];
    for (int i = t; i < 16; i += 256) b1d[i] = (double)b1[i];
    for (int i = t; i < 32; i += 256) b2d[i] = (double)b2[i];
    for (int i = t; i < 12; i += 256) b3d[i] = (double)b3[i];
    for (int i = t; i < 2048; i += 256) {  // w2d[k][o][c] = w2[o][c][k]
      int k = i >> 9, o = (i >> 4) & 31, c = i & 15;
      w2d[i] = (double)w2[o * 64 + c * 4 + k];
    }
    for (int i = t; i < 1536; i += 256) {  // w3d[q][j][o] = w3[j][o][q]
      int q = i / 384, r = i % 384, j = r >> 5, o = r & 31;
      w3d[i] = (double)w3[j * 128 + o * 4 + q];
    }
    for (int i = t; i < 1536; i += 256) {  // d1r[p][o][c] = d1w[c][o][p]
      int p = i / 384, r = i % 384, o = r / 12, c = r % 12;
      d1r[i] = d1w[c * 128 + o * 4 + p];
    }
    for (int i = t; i < 2048; i += 256) {  // d2r[k][o][c] = d2w[c][o][k]
      int k = i >> 9, o = (i >> 5) & 15, c = i & 31;
      d2r[i] = d2w[c * 64 + o * 4 + k];
    }
    for (int i = t; i < 64; i += 256) {    // d3r[k][c] = d3w[c][k]
      int k = i >> 4, c = i & 15;
      d3r[i] = d3w[c * 4 + k];
    }
  }
}

// ---------------------------------------------------------------------------
// encoder, fp64. Block = 512 = 8 waves, wave = (quarter qq, o-half oh);
// 2 window-sets per thread; conv2 c-chain split into 2 partials (2x chain
// ILP; fp64 reassociation decision-safe); weights in LDS; grid 256.
__global__ __launch_bounds__(512, 2) void k_enc(
    const float* __restrict__ x, const double* __restrict__ w1d,
    const double* __restrict__ w2d, const double* __restrict__ w3d,
    const double* __restrict__ b1d, const double* __restrict__ b2d,
    const double* __restrict__ b3d, float* __restrict__ cont_out,
    double* __restrict__ q64out, _Float16* __restrict__ q16out,
    unsigned* __restrict__ qmax) {
  __shared__ double w2s[2048];          // 16 KB
  __shared__ double w3s[1536];          // 12 KB
  __shared__ double w1s[64];
  __shared__ double b1s[16], b2s[32], b3s[12];
  __shared__ double red[2][8][64][12];  // 96 KB; total ~125 KB -> 1 block/CU

  int t = threadIdx.x;
  int gid0 = blockIdx.x * 512 + t;
  if (gid0 < 32768) qmax[gid0] = 0u;   // < okey(-3): any real score beats it

  for (int i = t; i < 2048; i += 512) w2s[i] = w2d[i];
  for (int i = t; i < 1536; i += 512) w3s[i] = w3d[i];
  if (t < 64) w1s[t] = w1d[t];
  else if (t >= 64 && t < 80) b1s[t - 64] = b1d[t - 64];
  else if (t >= 80 && t < 112) b2s[t - 80] = b2d[t - 80];
  else if (t >= 112 && t < 124) b3s[t - 112] = b3d[t - 112];
  __syncthreads();

  int w = t >> 6, lane = t & 63;
  int qq = w & 3, oh = w >> 2;
  int winA = blockIdx.x * 64 + lane;    // grid 256 -> sets 0..16383
  int winB = winA + 16384;
  const float* xbA = x + (winA >> 4) * 1024 + (winA & 15) * 64 + qq * 16;
  const float* xbB = x + (winB >> 4) * 1024 + (winB & 15) * 64 + qq * 16;

  double h2A[16], h2B[16];
#pragma unroll
  for (int o = 0; o < 16; o++) { h2A[o] = b2s[oh * 16 + o]; h2B[o] = h2A[o]; }

#pragma unroll 1
  for (int k = 0; k < 4; k++) {
    float4 xvA = *reinterpret_cast<const float4*>(xbA + 4 * k);
    float4 xvB = *reinterpret_cast<const float4*>(xbB + 4 * k);
    double xA0 = (double)xvA.x, xA1 = (double)xvA.y;
    double xA2 = (double)xvA.z, xA3 = (double)xvA.w;
    double xB0 = (double)xvB.x, xB1 = (double)xvB.y;
    double xB2 = (double)xvB.z, xB3 = (double)xvB.w;
    double h1A[16], h1B[16];
#pragma unroll
    for (int c = 0; c < 16; c++) {
      double2 wa = *(const double2*)(w1s + 4 * c);
      double2 wb = *(const double2*)(w1s + 4 * c + 2);
      double bb = b1s[c];
      double sA = bb, sB = bb;
      sA = fma(xA0, wa.x, sA); sB = fma(xB0, wa.x, sB);
      sA = fma(xA1, wa.y, sA); sB = fma(xB1, wa.y, sB);
      sA = fma(xA2, wb.x, sA); sB = fma(xB2, wb.x, sB);
      sA = fma(xA3, wb.y, sA); sB = fma(xB3, wb.y, sB);
      h1A[c] = sA > 0.0 ? sA : 0.0;
      h1B[c] = sB > 0.0 ? sB : 0.0;
    }
    const double* w2k = w2s + k * 512 + oh * 256;
#pragma unroll
    for (int o = 0; o < 16; o++) {
      const double* wp = w2k + o * 16;
      double sA0 = h2A[o], sA1 = 0.0, sB0 = h2B[o], sB1 = 0.0;
#pragma unroll
      for (int c = 0; c < 8; c += 2) {     // low half -> partial 0
        double2 wv = *(const double2*)(wp + c);
        sA0 = fma(h1A[c], wv.x, sA0); sA0 = fma(h1A[c + 1], wv.y, sA0);
        sB0 = fma(h1B[c], wv.x, sB0); sB0 = fma(h1B[c + 1], wv.y, sB0);
      }
#pragma unroll
      for (int c = 8; c < 16; c += 2) {    // high half -> partial 1
        double2 wv = *(const double2*)(wp + c);
        sA1 = fma(h1A[c], wv.x, sA1); sA1 = fma(h1A[c + 1], wv.y, sA1);
        sB1 = fma(h1B[c], wv.x, sB1); sB1 = fma(h1B[c + 1], wv.y, sB1);
      }
      h2A[o] = sA0 + sA1; h2B[o] = sB0 + sB1;
    }
  }
#pragma unroll
  for (int o = 0; o < 16; o++) {
    h2A[o] = h2A[o] > 0.0 ? h2A[o] : 0.0;
    h2B[o] = h2B[o] > 0.0 ? h2B[o] : 0.0;
  }

  const double* w3q = w3s + qq * 384 + oh * 16;
#pragma unroll
  for (int j = 0; j < 12; j++) {
    const double* wp = w3q + j * 32;
    double sA = 0.0, sB = 0.0;
#pragma unroll
    for (int o = 0; o < 16; o += 2) {
      double2 wv = *(const double2*)(wp + o);
      sA = fma(h2A[o], wv.x, sA); sA = fma(h2A[o + 1], wv.y, sA);
      sB = fma(h2B[o], wv.x, sB); sB = fma(h2B[o + 1], wv.y, sB);
    }
    red[0][w][lane][j] = sA;
    red[1][w][lane][j] = sB;
  }
  __syncthreads();

  if (w < 2) {  // wave 0 -> set A, wave 1 -> set B
    int set = w;
    int win = blockIdx.x * 64 + lane + set * 16384;
    int n = win >> 4, l = win & 15;
    double cont[12], ss = 0.0;
#pragma unroll
    for (int j = 0; j < 12; j++) {
      double v = b3s[j] +
          (((red[set][0][lane][j] + red[set][1][lane][j]) +
            (red[set][2][lane][j] + red[set][3][lane][j])) +
           ((red[set][4][lane][j] + red[set][5][lane][j]) +
            (red[set][6][lane][j] + red[set][7][lane][j])));
      cont[j] = v;
      ss = fma(v, v, ss);
    }
    double nrm = sqrt(ss);
    if (nrm < 1e-12) nrm = 1e-12;
    half8 lo, hi;
#pragma unroll
    for (int j = 0; j < 12; j++) {
      double qv = cont[j] / nrm;
      float qf = (float)qv;
      cont_out[n * 192 + j * 16 + l] = qf;
      q64out[(size_t)win * 12 + j] = qv;
      if (j < 8) lo[j] = (_Float16)qf; else hi[j - 8] = (_Float16)qf;
    }
#pragma unroll
    for (int j = 4; j < 8; j++) hi[j] = (_Float16)0.f;
    *(half8*)(q16out + (size_t)win * 16) = lo;
    *(half8*)(q16out + (size_t)win * 16 + 8) = hi;
  }
}

// ---------------------------------------------------------------------------
// VQ pass 1 (unchanged): per-query GLOBAL f16 max via distributed atomicMax.
// Barrier-free, depth-4 register prefetch from global; cq==0 blocks zero keys.
// D layout: col=lane&31, row=(reg&3)+8*(reg>>2)+4*(lane>>5)  [m74/m101]
__global__ __launch_bounds__(256, 4) void k_vq1(
    const _Float16* __restrict__ q16, const _Float16* __restrict__ cbf,
    unsigned* __restrict__ qmax, unsigned long long* __restrict__ keys) {
  int t = threadIdx.x;
  int w = t >> 6, lane = t & 63;
  int half = lane >> 5, col = lane & 31;
  int qg = blockIdx.x >> 3;  // 256 query groups of 128
  int cq = blockIdx.x & 7;   // 8 code chunks of 1024 (32 tiles)
  if (cq == 0 && t < 128) keys[qg * 128 + t] = 0ull;
  int qbase = qg * 128 + w * 32;
  const _Float16* bp = cbf + (size_t)cq * 32 * 64 * 8;

  half8 a = *(const half8*)(q16 + (size_t)(qbase + col) * 16 + half * 8);
  f32x16 z = {0.f, 0.f, 0.f, 0.f, 0.f, 0.f, 0.f, 0.f,
              0.f, 0.f, 0.f, 0.f, 0.f, 0.f, 0.f, 0.f};

  half8 b0 = *(const half8*)(bp + (0 * 64 + lane) * 8);
  half8 b1 = *(const half8*)(bp + (1 * 64 + lane) * 8);
  half8 b2 = *(const half8*)(bp + (2 * 64 + lane) * 8);
  half8 b3 = *(const half8*)(bp + (3 * 64 + lane) * 8);

  float mx[16];
#pragma unroll
  for (int r = 0; r < 16; r++) mx[r] = -3.f;

  f32x16 dp = __builtin_amdgcn_mfma_f32_32x32x16_f16(a, b0, z, 0, 0, 0);
  b0 = b1; b1 = b2; b2 = b3;
  b3 = *(const half8*)(bp + (4 * 64 + lane) * 8);

#pragma unroll 4
  for (int tt = 1; tt < 32; tt++) {
    f32x16 d = __builtin_amdgcn_mfma_f32_32x32x16_f16(a, b0, z, 0, 0, 0);
    b0 = b1; b1 = b2; b2 = b3;
    if (tt + 4 < 32) b3 = *(const half8*)(bp + ((tt + 4) * 64 + lane) * 8);
#pragma unroll
    for (int r = 0; r < 16; r++) mx[r] = fmaxf(mx[r], dp[r]);
    dp = d;
  }
#pragma unroll
  for (int r = 0; r < 16; r++) mx[r] = fmaxf(mx[r], dp[r]);

  // reduce across 32 columns (xor masks <=16 stay within each 32-half)
#pragma unroll
  for (int m = 1; m <= 16; m <<= 1) {
#pragma unroll
    for (int r = 0; r < 16; r++) mx[r] = fmaxf(mx[r], __shfl_xor(mx[r], m));
  }
  // lane col==r (one per half) publishes row max; addresses all distinct
#pragma unroll
  for (int r = 0; r < 16; r++) {
    if (col == r) {
      unsigned row = (r & 3) + 8 * (r >> 2) + 4 * half;
      atomicMax(&qmax[qbase + row], okey(mx[r]));
    }
  }
}

// ---------------------------------------------------------------------------
// VQ pass 2 (unchanged): barrier-free pipelined re-scan; candidates >= max -
// DELTA pushed to a per-wave LDS list; fp64 rescore at end (fma chain/key/
// tie-break identical to all passing rounds).
__global__ __launch_bounds__(256, 3) void k_vq2(
    const _Float16* __restrict__ q16, const _Float16* __restrict__ cbf,
    const unsigned* __restrict__ qmax, const double* __restrict__ q64,
    const float* __restrict__ cbk, const double* __restrict__ cchalf,
    unsigned long long* __restrict__ keys) {
  __shared__ unsigned wlist[4][WCAP];  // 8 KB
  __shared__ int wcnt[4];
  int t = threadIdx.x;
  int w = t >> 6, lane = t & 63;
  int half = lane >> 5, col = lane & 31;
  if (lane == 0) wcnt[w] = 0;   // per-wave, no block barrier needed
  int qg = blockIdx.x >> 3;
  int cq = blockIdx.x & 7;
  int qbase = qg * 128 + w * 32;
  int cbase = cq * 1024;
  const _Float16* bp = cbf + (size_t)cq * 32 * 64 * 8;

  half8 a = *(const half8*)(q16 + (size_t)(qbase + col) * 16 + half * 8);
  f32x16 z = {0.f, 0.f, 0.f, 0.f, 0.f, 0.f, 0.f, 0.f,
              0.f, 0.f, 0.f, 0.f, 0.f, 0.f, 0.f, 0.f};

  float thr[16];
#pragma unroll
  for (int r = 0; r < 16; r++) {
    unsigned row = (r & 3) + 8 * (r >> 2) + 4 * half;
    thr[r] = unokey(qmax[qbase + row]) - DELTA;
  }

  half8 b0 = *(const half8*)(bp + (0 * 64 + lane) * 8);
  half8 b1 = *(const half8*)(bp + (1 * 64 + lane) * 8);
  half8 b2 = *(const half8*)(bp + (2 * 64 + lane) * 8);
  half8 b3 = *(const half8*)(bp + (3 * 64 + lane) * 8);

#define CONSUME(dv, ttv)                                                      \
  {                                                                           \
    _Pragma("unroll") for (int r = 0; r < 16; r++) {                          \
      if (dv[r] >= thr[r]) {                                                  \
        int slot = atomicAdd(&wcnt[w], 1);                                    \
        unsigned row = (r & 3) + 8 * (r >> 2) + 4 * half;                     \
        unsigned enc = ((unsigned)(qbase + row) << 13) |                      \
                       (unsigned)(cbase + (ttv)*32 + col);                    \
        if (slot < WCAP) wlist[w][slot] = enc;                                \
      }                                                                       \
    }                                                                         \
  }

  f32x16 dp = __builtin_amdgcn_mfma_f32_32x32x16_f16(a, b0, z, 0, 0, 0);
  b0 = b1; b1 = b2; b2 = b3;
  b3 = *(const half8*)(bp + (4 * 64 + lane) * 8);

#pragma unroll 4
  for (int tt = 1; tt < 32; tt++) {
    f32x16 d = __builtin_amdgcn_mfma_f32_32x32x16_f16(a, b0, z, 0, 0, 0);
    b0 = b1; b1 = b2; b2 = b3;
    if (tt + 4 < 32) b3 = *(const half8*)(bp + ((tt + 4) * 64 + lane) * 8);
    CONSUME(dp, tt - 1);
    dp = d;
  }
  CONSUME(dp, 31);
#undef CONSUME

  // rescore this wave's candidates exactly in fp64 (chain matches passing)
  int n = wcnt[w];
  if (n > WCAP) n = WCAP;
  for (int i = lane; i < n; i += 64) {
    unsigned e = wlist[w][i];
    int q = e >> 13, c = e & 8191;
    const double* qp = q64 + (size_t)q * 12;
    const float* cp = cbk + c * 12;
    double s = 0.0;
#pragma unroll
    for (int dd = 0; dd < 12; dd++) s = fma(qp[dd], (double)cp[dd], s);
    unsigned long long ek =
        (unsigned long long)((s - cchalf[c] + 2.0) * SCALE46);
    atomicMax(&keys[q], (ek << 16) | (unsigned)(8191 - c));
  }
}

// ---------------------------------------------------------------------------
// decoder (fp32), fused with unpack. Block = 512 = 8 waves: wave = (p2, kh);
// each wave computes y1 (dup x2) then its 2 k-iterations -> 4096 waves total
// (4/SIMD). quant_out written by wave 0. LAUNCHED WITH 512 THREADS.
__global__ __launch_bounds__(512, 4) void k_dec(
    const unsigned long long* __restrict__ keys,
    const float* __restrict__ cbk, const float* __restrict__ d1r,
    const float* __restrict__ d2r, const float* __restrict__ d3r,
    const float* __restrict__ d1b, const float* __restrict__ d2b,
    const float* __restrict__ d3b, float* __restrict__ quant_out,
    float* __restrict__ rec) {
  int t = threadIdx.x;
  int w = t >> 6, lane = t & 63;
  int p2 = w & 3, kh = w >> 2;
  int win = blockIdx.x * 64 + lane;  // grid 512 -> 32768
  int gidx = 8191 - (int)(keys[win] & 0xFFFFull);
  const float* cp = cbk + gidx * 12;
  float4 q0 = *(const float4*)(cp);
  float4 q1 = *(const float4*)(cp + 4);
  float4 q2 = *(const float4*)(cp + 8);

  if (w == 0) {
    int n = win >> 4, l = win & 15;
    float* qo = quant_out + n * 192 + l;
    qo[0] = q0.x;  qo[16] = q0.y;  qo[32] = q0.z;  qo[48] = q0.w;
    qo[64] = q1.x; qo[80] = q1.y;  qo[96] = q1.z;  qo[112] = q1.w;
    qo[128] = q2.x; qo[144] = q2.y; qo[160] = q2.z; qo[176] = q2.w;
  }

  const float* d1p = d1r + p2 * 384;
  float y1[32];
#pragma unroll
  for (int o = 0; o < 32; o++) {
    const float4* wp = reinterpret_cast<const float4*>(d1p + o * 12);
    float4 a0 = wp[0], a1 = wp[1], a2 = wp[2];
    float s = d1b[o];
    s = fmaf(q0.x, a0.x, s); s = fmaf(q0.y, a0.y, s);
    s = fmaf(q0.z, a0.z, s); s = fmaf(q0.w, a0.w, s);
    s = fmaf(q1.x, a1.x, s); s = fmaf(q1.y, a1.y, s);
    s = fmaf(q1.z, a1.z, s); s = fmaf(q1.w, a1.w, s);
    s = fmaf(q2.x, a2.x, s); s = fmaf(q2.y, a2.y, s);
    s = fmaf(q2.z, a2.z, s); s = fmaf(q2.w, a2.w, s);
    y1[o] = relu(s);
  }

  float d3bias = d3b[0];
#pragma unroll
  for (int kk2 = 0; kk2 < 2; kk2++) {
    int k = kh * 2 + kk2;
    const float* d2k = d2r + k * 512;
    float y2[16];
#pragma unroll
    for (int o = 0; o < 16; o++) {
      const float4* wp = reinterpret_cast<const float4*>(d2k + o * 32);
      float s = d2b[o];
#pragma unroll
      for (int g = 0; g < 8; g++) {
        float4 a = wp[g];
        s = fmaf(y1[4 * g + 0], a.x, s); s = fmaf(y1[4 * g + 1], a.y, s);
        s = fmaf(y1[4 * g + 2], a.z, s); s = fmaf(y1[4 * g + 3], a.w, s);
      }
      y2[o] = relu(s);
    }
    float ov[4];
#pragma unroll
    for (int kk = 0; kk < 4; kk++) {
      const float4* wp = reinterpret_cast<const float4*>(d3r + kk * 16);
      float s = d3bias;
#pragma unroll
      for (int g = 0; g < 4; g++) {
        float4 a = wp[g];
        s = fmaf(y2[4 * g + 0], a.x, s); s = fmaf(y2[4 * g + 1], a.y, s);
        s = fmaf(y2[4 * g + 2], a.z, s); s = fmaf(y2[4 * g + 3], a.w, s);
      }
      ov[kk] = s;
    }
    *reinterpret_cast<float4*>(rec + win * 64 + p2 * 16 + k * 4) =
        make_float4(ov[0], ov[1], ov[2], ov[3]);
  }
}

// ---------------------------------------------------------------------------
extern "C" void kernel_launch(void* const* d_in, const int* in_sizes, int n_in,
                              void* d_out, int out_size, void* d_ws,
                              size_t ws_size, hipStream_t stream) {
  const float* x  = (const float*)d_in[0];
  const float* w1 = (const float*)d_in[1];
  const float* b1 = (const float*)d_in[2];
  const float* w2 = (const float*)d_in[3];
  const float* b2 = (const float*)d_in[4];
  const float* w3 = (const float*)d_in[5];
  const float* b3 = (const float*)d_in[6];
  int cb_idx = (in_sizes[13] == 98304) ? 13 : 7;
  int dbase = (cb_idx == 13) ? 7 : 8;
  const float* cbk = (const float*)d_in[cb_idx];
  const float* d1w = (const float*)d_in[dbase + 0];
  const float* d1b = (const float*)d_in[dbase + 1];
  const float* d2w = (const float*)d_in[dbase + 2];
  const float* d2b = (const float*)d_in[dbase + 3];
  const float* d3w = (const float*)d_in[dbase + 4];
  const float* d3b = (const float*)d_in[dbase + 5];

  float* out = (float*)d_out;
  float* rec = out;                 // (2048,1,1024)
  float* cont_out = out + 2097152;  // (2048,12,16)
  float* quant_out = out + 2490368; // (2048,12,16)

  char* wsb = (char*)d_ws;
  double* q64 = (double*)(wsb + WSB_Q64);
  unsigned* qmax = (unsigned*)(wsb + WSB_QZ);
  unsigned long long* keys = (unsigned long long*)(wsb + WSB_KEYS);
  double* cch = (double*)(wsb + WSB_CCH);
  double* w1d = (double*)(wsb + WSB_W1D);
  double* w2d = (double*)(wsb + WSB_W2D);
  double* w3d = (double*)(wsb + WSB_W3D);
  double* b1d = (double*)(wsb + WSB_B1D);
  double* b2d = (double*)(wsb + WSB_B2D);
  double* b3d = (double*)(wsb + WSB_B3D);
  float* d1r = (float*)(wsb + WSB_D1R);
  float* d2r = (float*)(wsb + WSB_D2R);
  float* d3r = (float*)(wsb + WSB_D3R);
  _Float16* cb16 = (_Float16*)(wsb + WSB_CB16);
  _Float16* q16 = (_Float16*)(wsb + WSB_Q16);

  k_prep<<<32, 256, 0, stream>>>(w1, b1, w2, b2, w3, b3, cbk, d1w, d2w, d3w,
                                 cch, w1d, w2d, w3d, b1d, b2d, b3d,
                                 d1r, d2r, d3r, cb16);
  k_enc<<<256, 512, 0, stream>>>(x, w1d, w2d, w3d, b1d, b2d, b3d, cont_out,
                                 q64, q16, qmax);
  k_vq1<<<2048, 256, 0, stream>>>(q16, cb16, qmax, keys);
  k_vq2<<<2048, 256, 0, stream>>>(q16, cb16, qmax, q64, cbk, cch, keys);
  k_dec<<<512, 512, 0, stream>>>(keys, cbk, d1r, d2r, d3r, d1b, d2b, d3b,
                                 quant_out, rec);
}

// Round 18
// 141.437 us; speedup vs baseline: 1.1252x; 1.1252x over previous
//
#include <hip/hip_runtime.h>
#include <math.h>

// ---------------------------------------------------------------------------
// SphericalConvCodec. fp64 decision path (encoder + exact rescore) matches the
// fp64 numpy reference; VQ scan uses f16 MFMA (32x32x16), two barrier-free
// kernels reading the L2-resident codebook straight from global. Round 18:
// k_enc reverted to round-15 form (round 17's chain split spilled: FETCH 62MB;
// this kernel sits at the 128-VGPR cliff); k_dec keeps the 8-wave split with
// the corrected 512-thread launch.
// codebook = d_in[13] (dict-literal order puts it after decoder weights).
// ws layout (byte offsets):
#define WSB_Q64   0u         // 32768*12 double  (3145728 B)
#define WSB_QZ    3145728u   // qmax u32[32768] lives here
#define WSB_KEYS  4718592u   // 32768 u64        (262144 B)
#define WSB_CCH   4980736u   // 8192 double      (65536 B)
#define WSB_W1D   5046272u   // 64 double
#define WSB_W2D   5046784u   // 2048 double [k][o][c]
#define WSB_W3D   5063168u   // 1536 double [q][j][o]
#define WSB_B1D   5075456u   // 16 double
#define WSB_B2D   5075584u   // 32 double
#define WSB_B3D   5075840u   // 12 double
#define WSB_D1R   5075936u   // 1536 float [p][o][c]
#define WSB_D2R   5082080u   // 2048 float [k][o][c]
#define WSB_D3R   5090272u   // 64 float  [k][c]
#define WSB_CB16  5090528u   // 8192*16 _Float16, FRAGMENT-ORDERED [tile][half][col][8]
#define WSB_Q16   5352672u   // 32768*16 _Float16 (1048576 B)
#define DELTA 0.003f
#define SCALE46 70368744177664.0  // 2^46
#define WCAP 512

typedef _Float16 half8 __attribute__((ext_vector_type(8)));
typedef float f32x16 __attribute__((ext_vector_type(16)));

__device__ __forceinline__ float relu(float v) { return v > 0.f ? v : 0.f; }

// monotone float<->uint order transform (valid for all finite floats)
__device__ __forceinline__ unsigned okey(float s) {
  unsigned u = __float_as_uint(s);
  return u ^ ((u & 0x80000000u) ? 0xFFFFFFFFu : 0x80000000u);
}
__device__ __forceinline__ float unokey(unsigned k) {
  unsigned u = k ^ ((k & 0x80000000u) ? 0x80000000u : 0xFFFFFFFFu);
  return __uint_as_float(u);
}

// ---------------------------------------------------------------------------
// prep (grid 32): cchalf fp64; cb16 fragment-ordered; block 0 repacks weights
__global__ __launch_bounds__(256) void k_prep(
    const float* __restrict__ w1, const float* __restrict__ b1,
    const float* __restrict__ w2, const float* __restrict__ b2,
    const float* __restrict__ w3, const float* __restrict__ b3,
    const float* __restrict__ cbk, const float* __restrict__ d1w,
    const float* __restrict__ d2w, const float* __restrict__ d3w,
    double* __restrict__ cch,
    double* __restrict__ w1d, double* __restrict__ w2d,
    double* __restrict__ w3d, double* __restrict__ b1d,
    double* __restrict__ b2d, double* __restrict__ b3d,
    float* __restrict__ d1r, float* __restrict__ d2r,
    float* __restrict__ d3r, _Float16* __restrict__ cb16) {
  int gid = blockIdx.x * 256 + threadIdx.x;  // grid 32 -> 8192
  if (gid < 8192) {
    double s = 0.0;
    half8 lo, hi;
#pragma unroll
    for (int d = 0; d < 12; d++) {
      float cf = cbk[gid * 12 + d];
      double c = (double)cf;
      s = fma(c, c, s);
      if (d < 8) lo[d] = (_Float16)cf; else hi[d - 8] = (_Float16)cf;
    }
#pragma unroll
    for (int d = 4; d < 8; d++) hi[d] = (_Float16)0.f;
    cch[gid] = 0.5 * s;
    // fragment order: tile = code>>5, col = code&31; half k-slice contiguous
    int tile = gid >> 5, col = gid & 31;
    *(half8*)(cb16 + (size_t)(tile * 64 + col) * 8) = lo;        // half 0
    *(half8*)(cb16 + (size_t)(tile * 64 + 32 + col) * 8) = hi;   // half 1
  }
  if (blockIdx.x == 0) {
    int t = threadIdx.x;
    for (int i = t; i < 64; i += 256) w1d[i] = (double)w1[i];
    for (int i = t; i < 16; i += 256) b1d[i] = (double)b1[i];
    for (int i = t; i < 32; i += 256) b2d[i] = (double)b2[i];
    for (int i = t; i < 12; i += 256) b3d[i] = (double)b3[i];
    for (int i = t; i < 2048; i += 256) {  // w2d[k][o][c] = w2[o][c][k]
      int k = i >> 9, o = (i >> 4) & 31, c = i & 15;
      w2d[i] = (double)w2[o * 64 + c * 4 + k];
    }
    for (int i = t; i < 1536; i += 256) {  // w3d[q][j][o] = w3[j][o][q]
      int q = i / 384, r = i % 384, j = r >> 5, o = r & 31;
      w3d[i] = (double)w3[j * 128 + o * 4 + q];
    }
    for (int i = t; i < 1536; i += 256) {  // d1r[p][o][c] = d1w[c][o][p]
      int p = i / 384, r = i % 384, o = r / 12, c = r % 12;
      d1r[i] = d1w[c * 128 + o * 4 + p];
    }
    for (int i = t; i < 2048; i += 256) {  // d2r[k][o][c] = d2w[c][o][k]
      int k = i >> 9, o = (i >> 5) & 15, c = i & 31;
      d2r[i] = d2w[c * 64 + o * 4 + k];
    }
    for (int i = t; i < 64; i += 256) {    // d3r[k][c] = d3w[c][k]
      int k = i >> 4, c = i & 15;
      d3r[i] = d3w[c * 4 + k];
    }
  }
}

// ---------------------------------------------------------------------------
// encoder, fp64 (round-15 form: no chain split -- that spilled). Block = 512
// = 8 waves, wave = (quarter qq, o-half oh); 2 window-sets per thread;
// weights in LDS; grid 256 (1 block/CU). Also zeroes qmax.
__global__ __launch_bounds__(512, 2) void k_enc(
    const float* __restrict__ x, const double* __restrict__ w1d,
    const double* __restrict__ w2d, const double* __restrict__ w3d,
    const double* __restrict__ b1d, const double* __restrict__ b2d,
    const double* __restrict__ b3d, float* __restrict__ cont_out,
    double* __restrict__ q64out, _Float16* __restrict__ q16out,
    unsigned* __restrict__ qmax) {
  __shared__ double w2s[2048];          // 16 KB
  __shared__ double w3s[1536];          // 12 KB
  __shared__ double w1s[64];
  __shared__ double b1s[16], b2s[32], b3s[12];
  __shared__ double red[2][8][64][12];  // 96 KB; total ~125 KB -> 1 block/CU

  int t = threadIdx.x;
  int gid0 = blockIdx.x * 512 + t;
  if (gid0 < 32768) qmax[gid0] = 0u;   // < okey(-3): any real score beats it

  for (int i = t; i < 2048; i += 512) w2s[i] = w2d[i];
  for (int i = t; i < 1536; i += 512) w3s[i] = w3d[i];
  if (t < 64) w1s[t] = w1d[t];
  else if (t >= 64 && t < 80) b1s[t - 64] = b1d[t - 64];
  else if (t >= 80 && t < 112) b2s[t - 80] = b2d[t - 80];
  else if (t >= 112 && t < 124) b3s[t - 112] = b3d[t - 112];
  __syncthreads();

  int w = t >> 6, lane = t & 63;
  int qq = w & 3, oh = w >> 2;
  int winA = blockIdx.x * 64 + lane;    // grid 256 -> sets 0..16383
  int winB = winA + 16384;
  const float* xbA = x + (winA >> 4) * 1024 + (winA & 15) * 64 + qq * 16;
  const float* xbB = x + (winB >> 4) * 1024 + (winB & 15) * 64 + qq * 16;

  double h2A[16], h2B[16];
#pragma unroll
  for (int o = 0; o < 16; o++) { h2A[o] = b2s[oh * 16 + o]; h2B[o] = h2A[o]; }

#pragma unroll 1
  for (int k = 0; k < 4; k++) {
    float4 xvA = *reinterpret_cast<const float4*>(xbA + 4 * k);
    float4 xvB = *reinterpret_cast<const float4*>(xbB + 4 * k);
    double xA0 = (double)xvA.x, xA1 = (double)xvA.y;
    double xA2 = (double)xvA.z, xA3 = (double)xvA.w;
    double xB0 = (double)xvB.x, xB1 = (double)xvB.y;
    double xB2 = (double)xvB.z, xB3 = (double)xvB.w;
    double h1A[16], h1B[16];
#pragma unroll
    for (int c = 0; c < 16; c++) {
      double2 wa = *(const double2*)(w1s + 4 * c);
      double2 wb = *(const double2*)(w1s + 4 * c + 2);
      double bb = b1s[c];
      double sA = bb, sB = bb;
      sA = fma(xA0, wa.x, sA); sB = fma(xB0, wa.x, sB);
      sA = fma(xA1, wa.y, sA); sB = fma(xB1, wa.y, sB);
      sA = fma(xA2, wb.x, sA); sB = fma(xB2, wb.x, sB);
      sA = fma(xA3, wb.y, sA); sB = fma(xB3, wb.y, sB);
      h1A[c] = sA > 0.0 ? sA : 0.0;
      h1B[c] = sB > 0.0 ? sB : 0.0;
    }
    const double* w2k = w2s + k * 512 + oh * 256;
#pragma unroll
    for (int o = 0; o < 16; o++) {
      const double* wp = w2k + o * 16;
      double sA = h2A[o], sB = h2B[o];
#pragma unroll
      for (int c = 0; c < 16; c += 2) {
        double2 wv = *(const double2*)(wp + c);
        sA = fma(h1A[c], wv.x, sA); sA = fma(h1A[c + 1], wv.y, sA);
        sB = fma(h1B[c], wv.x, sB); sB = fma(h1B[c + 1], wv.y, sB);
      }
      h2A[o] = sA; h2B[o] = sB;
    }
  }
#pragma unroll
  for (int o = 0; o < 16; o++) {
    h2A[o] = h2A[o] > 0.0 ? h2A[o] : 0.0;
    h2B[o] = h2B[o] > 0.0 ? h2B[o] : 0.0;
  }

  const double* w3q = w3s + qq * 384 + oh * 16;
#pragma unroll
  for (int j = 0; j < 12; j++) {
    const double* wp = w3q + j * 32;
    double sA = 0.0, sB = 0.0;
#pragma unroll
    for (int o = 0; o < 16; o += 2) {
      double2 wv = *(const double2*)(wp + o);
      sA = fma(h2A[o], wv.x, sA); sA = fma(h2A[o + 1], wv.y, sA);
      sB = fma(h2B[o], wv.x, sB); sB = fma(h2B[o + 1], wv.y, sB);
    }
    red[0][w][lane][j] = sA;
    red[1][w][lane][j] = sB;
  }
  __syncthreads();

  if (w < 2) {  // wave 0 -> set A, wave 1 -> set B
    int set = w;
    int win = blockIdx.x * 64 + lane + set * 16384;
    int n = win >> 4, l = win & 15;
    double cont[12], ss = 0.0;
#pragma unroll
    for (int j = 0; j < 12; j++) {
      double v = b3s[j] +
          (((red[set][0][lane][j] + red[set][1][lane][j]) +
            (red[set][2][lane][j] + red[set][3][lane][j])) +
           ((red[set][4][lane][j] + red[set][5][lane][j]) +
            (red[set][6][lane][j] + red[set][7][lane][j])));
      cont[j] = v;
      ss = fma(v, v, ss);
    }
    double nrm = sqrt(ss);
    if (nrm < 1e-12) nrm = 1e-12;
    half8 lo, hi;
#pragma unroll
    for (int j = 0; j < 12; j++) {
      double qv = cont[j] / nrm;
      float qf = (float)qv;
      cont_out[n * 192 + j * 16 + l] = qf;
      q64out[(size_t)win * 12 + j] = qv;
      if (j < 8) lo[j] = (_Float16)qf; else hi[j - 8] = (_Float16)qf;
    }
#pragma unroll
    for (int j = 4; j < 8; j++) hi[j] = (_Float16)0.f;
    *(half8*)(q16out + (size_t)win * 16) = lo;
    *(half8*)(q16out + (size_t)win * 16 + 8) = hi;
  }
}

// ---------------------------------------------------------------------------
// VQ pass 1 (unchanged): per-query GLOBAL f16 max via distributed atomicMax.
// Barrier-free, depth-4 register prefetch from global; cq==0 blocks zero keys.
// D layout: col=lane&31, row=(reg&3)+8*(reg>>2)+4*(lane>>5)  [m74/m101]
__global__ __launch_bounds__(256, 4) void k_vq1(
    const _Float16* __restrict__ q16, const _Float16* __restrict__ cbf,
    unsigned* __restrict__ qmax, unsigned long long* __restrict__ keys) {
  int t = threadIdx.x;
  int w = t >> 6, lane = t & 63;
  int half = lane >> 5, col = lane & 31;
  int qg = blockIdx.x >> 3;  // 256 query groups of 128
  int cq = blockIdx.x & 7;   // 8 code chunks of 1024 (32 tiles)
  if (cq == 0 && t < 128) keys[qg * 128 + t] = 0ull;
  int qbase = qg * 128 + w * 32;
  const _Float16* bp = cbf + (size_t)cq * 32 * 64 * 8;

  half8 a = *(const half8*)(q16 + (size_t)(qbase + col) * 16 + half * 8);
  f32x16 z = {0.f, 0.f, 0.f, 0.f, 0.f, 0.f, 0.f, 0.f,
              0.f, 0.f, 0.f, 0.f, 0.f, 0.f, 0.f, 0.f};

  half8 b0 = *(const half8*)(bp + (0 * 64 + lane) * 8);
  half8 b1 = *(const half8*)(bp + (1 * 64 + lane) * 8);
  half8 b2 = *(const half8*)(bp + (2 * 64 + lane) * 8);
  half8 b3 = *(const half8*)(bp + (3 * 64 + lane) * 8);

  float mx[16];
#pragma unroll
  for (int r = 0; r < 16; r++) mx[r] = -3.f;

  f32x16 dp = __builtin_amdgcn_mfma_f32_32x32x16_f16(a, b0, z, 0, 0, 0);
  b0 = b1; b1 = b2; b2 = b3;
  b3 = *(const half8*)(bp + (4 * 64 + lane) * 8);

#pragma unroll 4
  for (int tt = 1; tt < 32; tt++) {
    f32x16 d = __builtin_amdgcn_mfma_f32_32x32x16_f16(a, b0, z, 0, 0, 0);
    b0 = b1; b1 = b2; b2 = b3;
    if (tt + 4 < 32) b3 = *(const half8*)(bp + ((tt + 4) * 64 + lane) * 8);
#pragma unroll
    for (int r = 0; r < 16; r++) mx[r] = fmaxf(mx[r], dp[r]);
    dp = d;
  }
#pragma unroll
  for (int r = 0; r < 16; r++) mx[r] = fmaxf(mx[r], dp[r]);

  // reduce across 32 columns (xor masks <=16 stay within each 32-half)
#pragma unroll
  for (int m = 1; m <= 16; m <<= 1) {
#pragma unroll
    for (int r = 0; r < 16; r++) mx[r] = fmaxf(mx[r], __shfl_xor(mx[r], m));
  }
  // lane col==r (one per half) publishes row max; addresses all distinct
#pragma unroll
  for (int r = 0; r < 16; r++) {
    if (col == r) {
      unsigned row = (r & 3) + 8 * (r >> 2) + 4 * half;
      atomicMax(&qmax[qbase + row], okey(mx[r]));
    }
  }
}

// ---------------------------------------------------------------------------
// VQ pass 2 (unchanged): barrier-free pipelined re-scan; candidates >= max -
// DELTA pushed to a per-wave LDS list; fp64 rescore at end (fma chain/key/
// tie-break identical to all passing rounds).
__global__ __launch_bounds__(256, 3) void k_vq2(
    const _Float16* __restrict__ q16, const _Float16* __restrict__ cbf,
    const unsigned* __restrict__ qmax, const double* __restrict__ q64,
    const float* __restrict__ cbk, const double* __restrict__ cchalf,
    unsigned long long* __restrict__ keys) {
  __shared__ unsigned wlist[4][WCAP];  // 8 KB
  __shared__ int wcnt[4];
  int t = threadIdx.x;
  int w = t >> 6, lane = t & 63;
  int half = lane >> 5, col = lane & 31;
  if (lane == 0) wcnt[w] = 0;   // per-wave, no block barrier needed
  int qg = blockIdx.x >> 3;
  int cq = blockIdx.x & 7;
  int qbase = qg * 128 + w * 32;
  int cbase = cq * 1024;
  const _Float16* bp = cbf + (size_t)cq * 32 * 64 * 8;

  half8 a = *(const half8*)(q16 + (size_t)(qbase + col) * 16 + half * 8);
  f32x16 z = {0.f, 0.f, 0.f, 0.f, 0.f, 0.f, 0.f, 0.f,
              0.f, 0.f, 0.f, 0.f, 0.f, 0.f, 0.f, 0.f};

  float thr[16];
#pragma unroll
  for (int r = 0; r < 16; r++) {
    unsigned row = (r & 3) + 8 * (r >> 2) + 4 * half;
    thr[r] = unokey(qmax[qbase + row]) - DELTA;
  }

  half8 b0 = *(const half8*)(bp + (0 * 64 + lane) * 8);
  half8 b1 = *(const half8*)(bp + (1 * 64 + lane) * 8);
  half8 b2 = *(const half8*)(bp + (2 * 64 + lane) * 8);
  half8 b3 = *(const half8*)(bp + (3 * 64 + lane) * 8);

#define CONSUME(dv, ttv)                                                      \
  {                                                                           \
    _Pragma("unroll") for (int r = 0; r < 16; r++) {                          \
      if (dv[r] >= thr[r]) {                                                  \
        int slot = atomicAdd(&wcnt[w], 1);                                    \
        unsigned row = (r & 3) + 8 * (r >> 2) + 4 * half;                     \
        unsigned enc = ((unsigned)(qbase + row) << 13) |                      \
                       (unsigned)(cbase + (ttv)*32 + col);                    \
        if (slot < WCAP) wlist[w][slot] = enc;                                \
      }                                                                       \
    }                                                                         \
  }

  f32x16 dp = __builtin_amdgcn_mfma_f32_32x32x16_f16(a, b0, z, 0, 0, 0);
  b0 = b1; b1 = b2; b2 = b3;
  b3 = *(const half8*)(bp + (4 * 64 + lane) * 8);

#pragma unroll 4
  for (int tt = 1; tt < 32; tt++) {
    f32x16 d = __builtin_amdgcn_mfma_f32_32x32x16_f16(a, b0, z, 0, 0, 0);
    b0 = b1; b1 = b2; b2 = b3;
    if (tt + 4 < 32) b3 = *(const half8*)(bp + ((tt + 4) * 64 + lane) * 8);
    CONSUME(dp, tt - 1);
    dp = d;
  }
  CONSUME(dp, 31);
#undef CONSUME

  // rescore this wave's candidates exactly in fp64 (chain matches passing)
  int n = wcnt[w];
  if (n > WCAP) n = WCAP;
  for (int i = lane; i < n; i += 64) {
    unsigned e = wlist[w][i];
    int q = e >> 13, c = e & 8191;
    const double* qp = q64 + (size_t)q * 12;
    const float* cp = cbk + c * 12;
    double s = 0.0;
#pragma unroll
    for (int dd = 0; dd < 12; dd++) s = fma(qp[dd], (double)cp[dd], s);
    unsigned long long ek =
        (unsigned long long)((s - cchalf[c] + 2.0) * SCALE46);
    atomicMax(&keys[q], (ek << 16) | (unsigned)(8191 - c));
  }
}

// ---------------------------------------------------------------------------
// decoder (fp32), fused with unpack. Block = 512 = 8 waves: wave = (p2, kh);
// each wave computes y1 (dup x2) then its 2 k-iterations -> 4096 waves total
// (4/SIMD). quant_out written by wave 0.
__global__ __launch_bounds__(512, 4) void k_dec(
    const unsigned long long* __restrict__ keys,
    const float* __restrict__ cbk, const float* __restrict__ d1r,
    const float* __restrict__ d2r, const float* __restrict__ d3r,
    const float* __restrict__ d1b, const float* __restrict__ d2b,
    const float* __restrict__ d3b, float* __restrict__ quant_out,
    float* __restrict__ rec) {
  int t = threadIdx.x;
  int w = t >> 6, lane = t & 63;
  int p2 = w & 3, kh = w >> 2;
  int win = blockIdx.x * 64 + lane;  // grid 512 -> 32768
  int gidx = 8191 - (int)(keys[win] & 0xFFFFull);
  const float* cp = cbk + gidx * 12;
  float4 q0 = *(const float4*)(cp);
  float4 q1 = *(const float4*)(cp + 4);
  float4 q2 = *(const float4*)(cp + 8);

  if (w == 0) {
    int n = win >> 4, l = win & 15;
    float* qo = quant_out + n * 192 + l;
    qo[0] = q0.x;  qo[16] = q0.y;  qo[32] = q0.z;  qo[48] = q0.w;
    qo[64] = q1.x; qo[80] = q1.y;  qo[96] = q1.z;  qo[112] = q1.w;
    qo[128] = q2.x; qo[144] = q2.y; qo[160] = q2.z; qo[176] = q2.w;
  }

  const float* d1p = d1r + p2 * 384;
  float y1[32];
#pragma unroll
  for (int o = 0; o < 32; o++) {
    const float4* wp = reinterpret_cast<const float4*>(d1p + o * 12);
    float4 a0 = wp[0], a1 = wp[1], a2 = wp[2];
    float s = d1b[o];
    s = fmaf(q0.x, a0.x, s); s = fmaf(q0.y, a0.y, s);
    s = fmaf(q0.z, a0.z, s); s = fmaf(q0.w, a0.w, s);
    s = fmaf(q1.x, a1.x, s); s = fmaf(q1.y, a1.y, s);
    s = fmaf(q1.z, a1.z, s); s = fmaf(q1.w, a1.w, s);
    s = fmaf(q2.x, a2.x, s); s = fmaf(q2.y, a2.y, s);
    s = fmaf(q2.z, a2.z, s); s = fmaf(q2.w, a2.w, s);
    y1[o] = relu(s);
  }

  float d3bias = d3b[0];
#pragma unroll
  for (int kk2 = 0; kk2 < 2; kk2++) {
    int k = kh * 2 + kk2;
    const float* d2k = d2r + k * 512;
    float y2[16];
#pragma unroll
    for (int o = 0; o < 16; o++) {
      const float4* wp = reinterpret_cast<const float4*>(d2k + o * 32);
      float s = d2b[o];
#pragma unroll
      for (int g = 0; g < 8; g++) {
        float4 a = wp[g];
        s = fmaf(y1[4 * g + 0], a.x, s); s = fmaf(y1[4 * g + 1], a.y, s);
        s = fmaf(y1[4 * g + 2], a.z, s); s = fmaf(y1[4 * g + 3], a.w, s);
      }
      y2[o] = relu(s);
    }
    float ov[4];
#pragma unroll
    for (int kk = 0; kk < 4; kk++) {
      const float4* wp = reinterpret_cast<const float4*>(d3r + kk * 16);
      float s = d3bias;
#pragma unroll
      for (int g = 0; g < 4; g++) {
        float4 a = wp[g];
        s = fmaf(y2[4 * g + 0], a.x, s); s = fmaf(y2[4 * g + 1], a.y, s);
        s = fmaf(y2[4 * g + 2], a.z, s); s = fmaf(y2[4 * g + 3], a.w, s);
      }
      ov[kk] = s;
    }
    *reinterpret_cast<float4*>(rec + win * 64 + p2 * 16 + k * 4) =
        make_float4(ov[0], ov[1], ov[2], ov[3]);
  }
}

// ---------------------------------------------------------------------------
extern "C" void kernel_launch(void* const* d_in, const int* in_sizes, int n_in,
                              void* d_out, int out_size, void* d_ws,
                              size_t ws_size, hipStream_t stream) {
  const float* x  = (const float*)d_in[0];
  const float* w1 = (const float*)d_in[1];
  const float* b1 = (const float*)d_in[2];
  const float* w2 = (const float*)d_in[3];
  const float* b2 = (const float*)d_in[4];
  const float* w3 = (const float*)d_in[5];
  const float* b3 = (const float*)d_in[6];
  int cb_idx = (in_sizes[13] == 98304) ? 13 : 7;
  int dbase = (cb_idx == 13) ? 7 : 8;
  const float* cbk = (const float*)d_in[cb_idx];
  const float* d1w = (const float*)d_in[dbase + 0];
  const float* d1b = (const float*)d_in[dbase + 1];
  const float* d2w = (const float*)d_in[dbase + 2];
  const float* d2b = (const float*)d_in[dbase + 3];
  const float* d3w = (const float*)d_in[dbase + 4];
  const float* d3b = (const float*)d_in[dbase + 5];

  float* out = (float*)d_out;
  float* rec = out;                 // (2048,1,1024)
  float* cont_out = out + 2097152;  // (2048,12,16)
  float* quant_out = out + 2490368; // (2048,12,16)

  char* wsb = (char*)d_ws;
  double* q64 = (double*)(wsb + WSB_Q64);
  unsigned* qmax = (unsigned*)(wsb + WSB_QZ);
  unsigned long long* keys = (unsigned long long*)(wsb + WSB_KEYS);
  double* cch = (double*)(wsb + WSB_CCH);
  double* w1d = (double*)(wsb + WSB_W1D);
  double* w2d = (double*)(wsb + WSB_W2D);
  double* w3d = (double*)(wsb + WSB_W3D);
  double* b1d = (double*)(wsb + WSB_B1D);
  double* b2d = (double*)(wsb + WSB_B2D);
  double* b3d = (double*)(wsb + WSB_B3D);
  float* d1r = (float*)(wsb + WSB_D1R);
  float* d2r = (float*)(wsb + WSB_D2R);
  float* d3r = (float*)(wsb + WSB_D3R);
  _Float16* cb16 = (_Float16*)(wsb + WSB_CB16);
  _Float16* q16 = (_Float16*)(wsb + WSB_Q16);

  k_prep<<<32, 256, 0, stream>>>(w1, b1, w2, b2, w3, b3, cbk, d1w, d2w, d3w,
                                 cch, w1d, w2d, w3d, b1d, b2d, b3d,
                                 d1r, d2r, d3r, cb16);
  k_enc<<<256, 512, 0, stream>>>(x, w1d, w2d, w3d, b1d, b2d, b3d, cont_out,
                                 q64, q16, qmax);
  k_vq1<<<2048, 256, 0, stream>>>(q16, cb16, qmax, keys);
  k_vq2<<<2048, 256, 0, stream>>>(q16, cb16, qmax, q64, cbk, cch, keys);
  k_dec<<<512, 512, 0, stream>>>(keys, cbk, d1r, d2r, d3r, d1b, d2b, d3b,
                                 quant_out, rec);
}

// Round 19
// 117.839 us; speedup vs baseline: 1.3505x; 1.2003x over previous
//
#include <hip/hip_runtime.h>
#include <math.h>

// ---------------------------------------------------------------------------
// SphericalConvCodec. fp64 decision path (encoder + exact rescore) matches the
// fp64 numpy reference; VQ scan uses f16 MFMA (32x32x16), two barrier-free
// kernels reading the L2-resident codebook straight from global. Round 19:
// decoder restructured -- only 8192 distinct inputs exist, so k_pre decodes
// each CODE once into decoded[8192][64] (4x less work, LDS weights, fp32
// chains bit-identical to the passing k_dec) and k_gather scatters rows to
// rec/quant_out by key (pure bandwidth).
// codebook = d_in[13] (dict-literal order puts it after decoder weights).
// ws layout (byte offsets):
#define WSB_Q64   0u         // 32768*12 double; decoded[8192][64] f32 (2MB)
                             //   overlaps AFTER k_vq2 (q64 dead by then)
#define WSB_QZ    3145728u   // qmax u32[32768] lives here
#define WSB_KEYS  4718592u   // 32768 u64        (262144 B)
#define WSB_CCH   4980736u   // 8192 double      (65536 B)
#define WSB_W1D   5046272u   // 64 double
#define WSB_W2D   5046784u   // 2048 double [k][o][c]
#define WSB_W3D   5063168u   // 1536 double [q][j][o]
#define WSB_B1D   5075456u   // 16 double
#define WSB_B2D   5075584u   // 32 double
#define WSB_B3D   5075840u   // 12 double
#define WSB_D1R   5075936u   // 1536 float [p][o][c]
#define WSB_D2R   5082080u   // 2048 float [k][o][c]
#define WSB_D3R   5090272u   // 64 float  [k][c]
#define WSB_CB16  5090528u   // 8192*16 _Float16, FRAGMENT-ORDERED [tile][half][col][8]
#define WSB_Q16   5352672u   // 32768*16 _Float16 (1048576 B)
#define DELTA 0.003f
#define SCALE46 70368744177664.0  // 2^46
#define WCAP 512

typedef _Float16 half8 __attribute__((ext_vector_type(8)));
typedef float f32x16 __attribute__((ext_vector_type(16)));

__device__ __forceinline__ float relu(float v) { return v > 0.f ? v : 0.f; }

// monotone float<->uint order transform (valid for all finite floats)
__device__ __forceinline__ unsigned okey(float s) {
  unsigned u = __float_as_uint(s);
  return u ^ ((u & 0x80000000u) ? 0xFFFFFFFFu : 0x80000000u);
}
__device__ __forceinline__ float unokey(unsigned k) {
  unsigned u = k ^ ((k & 0x80000000u) ? 0x80000000u : 0xFFFFFFFFu);
  return __uint_as_float(u);
}

// ---------------------------------------------------------------------------
// prep (grid 32): cchalf fp64; cb16 fragment-ordered; block 0 repacks weights
__global__ __launch_bounds__(256) void k_prep(
    const float* __restrict__ w1, const float* __restrict__ b1,
    const float* __restrict__ w2, const float* __restrict__ b2,
    const float* __restrict__ w3, const float* __restrict__ b3,
    const float* __restrict__ cbk, const float* __restrict__ d1w,
    const float* __restrict__ d2w, const float* __restrict__ d3w,
    double* __restrict__ cch,
    double* __restrict__ w1d, double* __restrict__ w2d,
    double* __restrict__ w3d, double* __restrict__ b1d,
    double* __restrict__ b2d, double* __restrict__ b3d,
    float* __restrict__ d1r, float* __restrict__ d2r,
    float* __restrict__ d3r, _Float16* __restrict__ cb16) {
  int gid = blockIdx.x * 256 + threadIdx.x;  // grid 32 -> 8192
  if (gid < 8192) {
    double s = 0.0;
    half8 lo, hi;
#pragma unroll
    for (int d = 0; d < 12; d++) {
      float cf = cbk[gid * 12 + d];
      double c = (double)cf;
      s = fma(c, c, s);
      if (d < 8) lo[d] = (_Float16)cf; else hi[d - 8] = (_Float16)cf;
    }
#pragma unroll
    for (int d = 4; d < 8; d++) hi[d] = (_Float16)0.f;
    cch[gid] = 0.5 * s;
    // fragment order: tile = code>>5, col = code&31; half k-slice contiguous
    int tile = gid >> 5, col = gid & 31;
    *(half8*)(cb16 + (size_t)(tile * 64 + col) * 8) = lo;        // half 0
    *(half8*)(cb16 + (size_t)(tile * 64 + 32 + col) * 8) = hi;   // half 1
  }
  if (blockIdx.x == 0) {
    int t = threadIdx.x;
    for (int i = t; i < 64; i += 256) w1d[i] = (double)w1[i];
    for (int i = t; i < 16; i += 256) b1d[i] = (double)b1[i];
    for (int i = t; i < 32; i += 256) b2d[i] = (double)b2[i];
    for (int i = t; i < 12; i += 256) b3d[i] = (double)b3[i];
    for (int i = t; i < 2048; i += 256) {  // w2d[k][o][c] = w2[o][c][k]
      int k = i >> 9, o = (i >> 4) & 31, c = i & 15;
      w2d[i] = (double)w2[o * 64 + c * 4 + k];
    }
    for (int i = t; i < 1536; i += 256) {  // w3d[q][j][o] = w3[j][o][q]
      int q = i / 384, r = i % 384, j = r >> 5, o = r & 31;
      w3d[i] = (double)w3[j * 128 + o * 4 + q];
    }
    for (int i = t; i < 1536; i += 256) {  // d1r[p][o][c] = d1w[c][o][p]
      int p = i / 384, r = i % 384, o = r / 12, c = r % 12;
      d1r[i] = d1w[c * 128 + o * 4 + p];
    }
    for (int i = t; i < 2048; i += 256) {  // d2r[k][o][c] = d2w[c][o][k]
      int k = i >> 9, o = (i >> 5) & 15, c = i & 31;
      d2r[i] = d2w[c * 64 + o * 4 + k];
    }
    for (int i = t; i < 64; i += 256) {    // d3r[k][c] = d3w[c][k]
      int k = i >> 4, c = i & 15;
      d3r[i] = d3w[c * 4 + k];
    }
  }
}

// ---------------------------------------------------------------------------
// encoder, fp64 (round-15 form, measured good: FETCH ~4.3MB, no spill).
// Block = 512 = 8 waves, wave = (quarter qq, o-half oh); 2 window-sets per
// thread; weights in LDS; grid 256 (1 block/CU). Also zeroes qmax.
__global__ __launch_bounds__(512, 2) void k_enc(
    const float* __restrict__ x, const double* __restrict__ w1d,
    const double* __restrict__ w2d, const double* __restrict__ w3d,
    const double* __restrict__ b1d, const double* __restrict__ b2d,
    const double* __restrict__ b3d, float* __restrict__ cont_out,
    double* __restrict__ q64out, _Float16* __restrict__ q16out,
    unsigned* __restrict__ qmax) {
  __shared__ double w2s[2048];          // 16 KB
  __shared__ double w3s[1536];          // 12 KB
  __shared__ double w1s[64];
  __shared__ double b1s[16], b2s[32], b3s[12];
  __shared__ double red[2][8][64][12];  // 96 KB; total ~125 KB -> 1 block/CU

  int t = threadIdx.x;
  int gid0 = blockIdx.x * 512 + t;
  if (gid0 < 32768) qmax[gid0] = 0u;   // < okey(-3): any real score beats it

  for (int i = t; i < 2048; i += 512) w2s[i] = w2d[i];
  for (int i = t; i < 1536; i += 512) w3s[i] = w3d[i];
  if (t < 64) w1s[t] = w1d[t];
  else if (t >= 64 && t < 80) b1s[t - 64] = b1d[t - 64];
  else if (t >= 80 && t < 112) b2s[t - 80] = b2d[t - 80];
  else if (t >= 112 && t < 124) b3s[t - 112] = b3d[t - 112];
  __syncthreads();

  int w = t >> 6, lane = t & 63;
  int qq = w & 3, oh = w >> 2;
  int winA = blockIdx.x * 64 + lane;    // grid 256 -> sets 0..16383
  int winB = winA + 16384;
  const float* xbA = x + (winA >> 4) * 1024 + (winA & 15) * 64 + qq * 16;
  const float* xbB = x + (winB >> 4) * 1024 + (winB & 15) * 64 + qq * 16;

  double h2A[16], h2B[16];
#pragma unroll
  for (int o = 0; o < 16; o++) { h2A[o] = b2s[oh * 16 + o]; h2B[o] = h2A[o]; }

#pragma unroll 1
  for (int k = 0; k < 4; k++) {
    float4 xvA = *reinterpret_cast<const float4*>(xbA + 4 * k);
    float4 xvB = *reinterpret_cast<const float4*>(xbB + 4 * k);
    double xA0 = (double)xvA.x, xA1 = (double)xvA.y;
    double xA2 = (double)xvA.z, xA3 = (double)xvA.w;
    double xB0 = (double)xvB.x, xB1 = (double)xvB.y;
    double xB2 = (double)xvB.z, xB3 = (double)xvB.w;
    double h1A[16], h1B[16];
#pragma unroll
    for (int c = 0; c < 16; c++) {
      double2 wa = *(const double2*)(w1s + 4 * c);
      double2 wb = *(const double2*)(w1s + 4 * c + 2);
      double bb = b1s[c];
      double sA = bb, sB = bb;
      sA = fma(xA0, wa.x, sA); sB = fma(xB0, wa.x, sB);
      sA = fma(xA1, wa.y, sA); sB = fma(xB1, wa.y, sB);
      sA = fma(xA2, wb.x, sA); sB = fma(xB2, wb.x, sB);
      sA = fma(xA3, wb.y, sA); sB = fma(xB3, wb.y, sB);
      h1A[c] = sA > 0.0 ? sA : 0.0;
      h1B[c] = sB > 0.0 ? sB : 0.0;
    }
    const double* w2k = w2s + k * 512 + oh * 256;
#pragma unroll
    for (int o = 0; o < 16; o++) {
      const double* wp = w2k + o * 16;
      double sA = h2A[o], sB = h2B[o];
#pragma unroll
      for (int c = 0; c < 16; c += 2) {
        double2 wv = *(const double2*)(wp + c);
        sA = fma(h1A[c], wv.x, sA); sA = fma(h1A[c + 1], wv.y, sA);
        sB = fma(h1B[c], wv.x, sB); sB = fma(h1B[c + 1], wv.y, sB);
      }
      h2A[o] = sA; h2B[o] = sB;
    }
  }
#pragma unroll
  for (int o = 0; o < 16; o++) {
    h2A[o] = h2A[o] > 0.0 ? h2A[o] : 0.0;
    h2B[o] = h2B[o] > 0.0 ? h2B[o] : 0.0;
  }

  const double* w3q = w3s + qq * 384 + oh * 16;
#pragma unroll
  for (int j = 0; j < 12; j++) {
    const double* wp = w3q + j * 32;
    double sA = 0.0, sB = 0.0;
#pragma unroll
    for (int o = 0; o < 16; o += 2) {
      double2 wv = *(const double2*)(wp + o);
      sA = fma(h2A[o], wv.x, sA); sA = fma(h2A[o + 1], wv.y, sA);
      sB = fma(h2B[o], wv.x, sB); sB = fma(h2B[o + 1], wv.y, sB);
    }
    red[0][w][lane][j] = sA;
    red[1][w][lane][j] = sB;
  }
  __syncthreads();

  if (w < 2) {  // wave 0 -> set A, wave 1 -> set B
    int set = w;
    int win = blockIdx.x * 64 + lane + set * 16384;
    int n = win >> 4, l = win & 15;
    double cont[12], ss = 0.0;
#pragma unroll
    for (int j = 0; j < 12; j++) {
      double v = b3s[j] +
          (((red[set][0][lane][j] + red[set][1][lane][j]) +
            (red[set][2][lane][j] + red[set][3][lane][j])) +
           ((red[set][4][lane][j] + red[set][5][lane][j]) +
            (red[set][6][lane][j] + red[set][7][lane][j])));
      cont[j] = v;
      ss = fma(v, v, ss);
    }
    double nrm = sqrt(ss);
    if (nrm < 1e-12) nrm = 1e-12;
    half8 lo, hi;
#pragma unroll
    for (int j = 0; j < 12; j++) {
      double qv = cont[j] / nrm;
      float qf = (float)qv;
      cont_out[n * 192 + j * 16 + l] = qf;
      q64out[(size_t)win * 12 + j] = qv;
      if (j < 8) lo[j] = (_Float16)qf; else hi[j - 8] = (_Float16)qf;
    }
#pragma unroll
    for (int j = 4; j < 8; j++) hi[j] = (_Float16)0.f;
    *(half8*)(q16out + (size_t)win * 16) = lo;
    *(half8*)(q16out + (size_t)win * 16 + 8) = hi;
  }
}

// ---------------------------------------------------------------------------
// VQ pass 1 (unchanged): per-query GLOBAL f16 max via distributed atomicMax.
// Barrier-free, depth-4 register prefetch from global; cq==0 blocks zero keys.
// D layout: col=lane&31, row=(reg&3)+8*(reg>>2)+4*(lane>>5)  [m74/m101]
__global__ __launch_bounds__(256, 4) void k_vq1(
    const _Float16* __restrict__ q16, const _Float16* __restrict__ cbf,
    unsigned* __restrict__ qmax, unsigned long long* __restrict__ keys) {
  int t = threadIdx.x;
  int w = t >> 6, lane = t & 63;
  int half = lane >> 5, col = lane & 31;
  int qg = blockIdx.x >> 3;  // 256 query groups of 128
  int cq = blockIdx.x & 7;   // 8 code chunks of 1024 (32 tiles)
  if (cq == 0 && t < 128) keys[qg * 128 + t] = 0ull;
  int qbase = qg * 128 + w * 32;
  const _Float16* bp = cbf + (size_t)cq * 32 * 64 * 8;

  half8 a = *(const half8*)(q16 + (size_t)(qbase + col) * 16 + half * 8);
  f32x16 z = {0.f, 0.f, 0.f, 0.f, 0.f, 0.f, 0.f, 0.f,
              0.f, 0.f, 0.f, 0.f, 0.f, 0.f, 0.f, 0.f};

  half8 b0 = *(const half8*)(bp + (0 * 64 + lane) * 8);
  half8 b1 = *(const half8*)(bp + (1 * 64 + lane) * 8);
  half8 b2 = *(const half8*)(bp + (2 * 64 + lane) * 8);
  half8 b3 = *(const half8*)(bp + (3 * 64 + lane) * 8);

  float mx[16];
#pragma unroll
  for (int r = 0; r < 16; r++) mx[r] = -3.f;

  f32x16 dp = __builtin_amdgcn_mfma_f32_32x32x16_f16(a, b0, z, 0, 0, 0);
  b0 = b1; b1 = b2; b2 = b3;
  b3 = *(const half8*)(bp + (4 * 64 + lane) * 8);

#pragma unroll 4
  for (int tt = 1; tt < 32; tt++) {
    f32x16 d = __builtin_amdgcn_mfma_f32_32x32x16_f16(a, b0, z, 0, 0, 0);
    b0 = b1; b1 = b2; b2 = b3;
    if (tt + 4 < 32) b3 = *(const half8*)(bp + ((tt + 4) * 64 + lane) * 8);
#pragma unroll
    for (int r = 0; r < 16; r++) mx[r] = fmaxf(mx[r], dp[r]);
    dp = d;
  }
#pragma unroll
  for (int r = 0; r < 16; r++) mx[r] = fmaxf(mx[r], dp[r]);

  // reduce across 32 columns (xor masks <=16 stay within each 32-half)
#pragma unroll
  for (int m = 1; m <= 16; m <<= 1) {
#pragma unroll
    for (int r = 0; r < 16; r++) mx[r] = fmaxf(mx[r], __shfl_xor(mx[r], m));
  }
  // lane col==r (one per half) publishes row max; addresses all distinct
#pragma unroll
  for (int r = 0; r < 16; r++) {
    if (col == r) {
      unsigned row = (r & 3) + 8 * (r >> 2) + 4 * half;
      atomicMax(&qmax[qbase + row], okey(mx[r]));
    }
  }
}

// ---------------------------------------------------------------------------
// VQ pass 2 (unchanged): barrier-free pipelined re-scan; candidates >= max -
// DELTA pushed to a per-wave LDS list; fp64 rescore at end (fma chain/key/
// tie-break identical to all passing rounds).
__global__ __launch_bounds__(256, 3) void k_vq2(
    const _Float16* __restrict__ q16, const _Float16* __restrict__ cbf,
    const unsigned* __restrict__ qmax, const double* __restrict__ q64,
    const float* __restrict__ cbk, const double* __restrict__ cchalf,
    unsigned long long* __restrict__ keys) {
  __shared__ unsigned wlist[4][WCAP];  // 8 KB
  __shared__ int wcnt[4];
  int t = threadIdx.x;
  int w = t >> 6, lane = t & 63;
  int half = lane >> 5, col = lane & 31;
  if (lane == 0) wcnt[w] = 0;   // per-wave, no block barrier needed
  int qg = blockIdx.x >> 3;
  int cq = blockIdx.x & 7;
  int qbase = qg * 128 + w * 32;
  int cbase = cq * 1024;
  const _Float16* bp = cbf + (size_t)cq * 32 * 64 * 8;

  half8 a = *(const half8*)(q16 + (size_t)(qbase + col) * 16 + half * 8);
  f32x16 z = {0.f, 0.f, 0.f, 0.f, 0.f, 0.f, 0.f, 0.f,
              0.f, 0.f, 0.f, 0.f, 0.f, 0.f, 0.f, 0.f};

  float thr[16];
#pragma unroll
  for (int r = 0; r < 16; r++) {
    unsigned row = (r & 3) + 8 * (r >> 2) + 4 * half;
    thr[r] = unokey(qmax[qbase + row]) - DELTA;
  }

  half8 b0 = *(const half8*)(bp + (0 * 64 + lane) * 8);
  half8 b1 = *(const half8*)(bp + (1 * 64 + lane) * 8);
  half8 b2 = *(const half8*)(bp + (2 * 64 + lane) * 8);
  half8 b3 = *(const half8*)(bp + (3 * 64 + lane) * 8);

#define CONSUME(dv, ttv)                                                      \
  {                                                                           \
    _Pragma("unroll") for (int r = 0; r < 16; r++) {                          \
      if (dv[r] >= thr[r]) {                                                  \
        int slot = atomicAdd(&wcnt[w], 1);                                    \
        unsigned row = (r & 3) + 8 * (r >> 2) + 4 * half;                     \
        unsigned enc = ((unsigned)(qbase + row) << 13) |                      \
                       (unsigned)(cbase + (ttv)*32 + col);                    \
        if (slot < WCAP) wlist[w][slot] = enc;                                \
      }                                                                       \
    }                                                                         \
  }

  f32x16 dp = __builtin_amdgcn_mfma_f32_32x32x16_f16(a, b0, z, 0, 0, 0);
  b0 = b1; b1 = b2; b2 = b3;
  b3 = *(const half8*)(bp + (4 * 64 + lane) * 8);

#pragma unroll 4
  for (int tt = 1; tt < 32; tt++) {
    f32x16 d = __builtin_amdgcn_mfma_f32_32x32x16_f16(a, b0, z, 0, 0, 0);
    b0 = b1; b1 = b2; b2 = b3;
    if (tt + 4 < 32) b3 = *(const half8*)(bp + ((tt + 4) * 64 + lane) * 8);
    CONSUME(dp, tt - 1);
    dp = d;
  }
  CONSUME(dp, 31);
#undef CONSUME

  // rescore this wave's candidates exactly in fp64 (chain matches passing)
  int n = wcnt[w];
  if (n > WCAP) n = WCAP;
  for (int i = lane; i < n; i += 64) {
    unsigned e = wlist[w][i];
    int q = e >> 13, c = e & 8191;
    const double* qp = q64 + (size_t)q * 12;
    const float* cp = cbk + c * 12;
    double s = 0.0;
#pragma unroll
    for (int dd = 0; dd < 12; dd++) s = fma(qp[dd], (double)cp[dd], s);
    unsigned long long ek =
        (unsigned long long)((s - cchalf[c] + 2.0) * SCALE46);
    atomicMax(&keys[q], (ek << 16) | (unsigned)(8191 - c));
  }
}

// ---------------------------------------------------------------------------
// k_pre: decode ALL 8192 codebook rows once -> decoded[8192][64].
// Thread = (code, p2, kh): 65536 threads, grid 256 x 256. Weights in LDS.
// fp32 fma chains identical to the passing k_dec -> bit-identical rec values.
// Runs AFTER k_vq2 (overwrites the then-dead q64 region).
__global__ __launch_bounds__(256) void k_pre(
    const float* __restrict__ cbk, const float* __restrict__ d1r,
    const float* __restrict__ d2r, const float* __restrict__ d3r,
    const float* __restrict__ d1b, const float* __restrict__ d2b,
    const float* __restrict__ d3b, float* __restrict__ decoded) {
  __shared__ float w1s[1536], w2s[2048], w3s[64];
  __shared__ float b1s[32], b2s_[16];
  int t = threadIdx.x;
  for (int i = t; i < 1536; i += 256) w1s[i] = d1r[i];
  for (int i = t; i < 2048; i += 256) w2s[i] = d2r[i];
  if (t < 64) w3s[t] = d3r[t];
  else if (t >= 64 && t < 96) b1s[t - 64] = d1b[t - 64];
  else if (t >= 96 && t < 112) b2s_[t - 96] = d2b[t - 96];
  __syncthreads();

  int code = blockIdx.x * 32 + (t & 31);
  int p2 = (t >> 5) & 3;
  int kh = t >> 7;
  const float* cp = cbk + code * 12;
  float4 q0 = *(const float4*)(cp);
  float4 q1 = *(const float4*)(cp + 4);
  float4 q2 = *(const float4*)(cp + 8);

  const float* d1p = w1s + p2 * 384;
  float y1[32];
#pragma unroll
  for (int o = 0; o < 32; o++) {
    const float* wp = d1p + o * 12;
    float s = b1s[o];
    s = fmaf(q0.x, wp[0], s); s = fmaf(q0.y, wp[1], s);
    s = fmaf(q0.z, wp[2], s); s = fmaf(q0.w, wp[3], s);
    s = fmaf(q1.x, wp[4], s); s = fmaf(q1.y, wp[5], s);
    s = fmaf(q1.z, wp[6], s); s = fmaf(q1.w, wp[7], s);
    s = fmaf(q2.x, wp[8], s); s = fmaf(q2.y, wp[9], s);
    s = fmaf(q2.z, wp[10], s); s = fmaf(q2.w, wp[11], s);
    y1[o] = relu(s);
  }

  float d3bias = d3b[0];
#pragma unroll
  for (int kk2 = 0; kk2 < 2; kk2++) {
    int k = kh * 2 + kk2;
    const float* d2k = w2s + k * 512;
    float y2[16];
#pragma unroll
    for (int o = 0; o < 16; o++) {
      const float* wp = d2k + o * 32;
      float s = b2s_[o];
#pragma unroll
      for (int c = 0; c < 32; c += 4) {
        s = fmaf(y1[c + 0], wp[c + 0], s); s = fmaf(y1[c + 1], wp[c + 1], s);
        s = fmaf(y1[c + 2], wp[c + 2], s); s = fmaf(y1[c + 3], wp[c + 3], s);
      }
      y2[o] = relu(s);
    }
    float ov[4];
#pragma unroll
    for (int kk = 0; kk < 4; kk++) {
      const float* wp = w3s + kk * 16;
      float s = d3bias;
#pragma unroll
      for (int g = 0; g < 16; g += 4) {
        s = fmaf(y2[g + 0], wp[g + 0], s); s = fmaf(y2[g + 1], wp[g + 1], s);
        s = fmaf(y2[g + 2], wp[g + 2], s); s = fmaf(y2[g + 3], wp[g + 3], s);
      }
      ov[kk] = s;
    }
    *reinterpret_cast<float4*>(decoded + (size_t)code * 64 + p2 * 16 + k * 4) =
        make_float4(ov[0], ov[1], ov[2], ov[3]);
  }
}

// ---------------------------------------------------------------------------
// k_gather: rec[win] = decoded[key[win]]; quant_out gathered from codebook.
// Pure bandwidth (8.4MB write, decoded 2MB L2-resident).
__global__ __launch_bounds__(256) void k_gather(
    const unsigned long long* __restrict__ keys,
    const float* __restrict__ decoded, const float* __restrict__ cbk,
    float* __restrict__ quant_out, float* __restrict__ rec) {
  int g = blockIdx.x * 256 + threadIdx.x;  // grid 2048 -> 524288
  int win = g >> 4, i = g & 15;
  int gidx = 8191 - (int)(keys[win] & 0xFFFFull);
  float4 v = ((const float4*)(decoded + (size_t)gidx * 64))[i];
  ((float4*)(rec + (size_t)win * 64))[i] = v;
  if (i < 12) {
    int n = win >> 4, l = win & 15;
    quant_out[n * 192 + i * 16 + l] = cbk[gidx * 12 + i];
  }
}

// ---------------------------------------------------------------------------
extern "C" void kernel_launch(void* const* d_in, const int* in_sizes, int n_in,
                              void* d_out, int out_size, void* d_ws,
                              size_t ws_size, hipStream_t stream) {
  const float* x  = (const float*)d_in[0];
  const float* w1 = (const float*)d_in[1];
  const float* b1 = (const float*)d_in[2];
  const float* w2 = (const float*)d_in[3];
  const float* b2 = (const float*)d_in[4];
  const float* w3 = (const float*)d_in[5];
  const float* b3 = (const float*)d_in[6];
  int cb_idx = (in_sizes[13] == 98304) ? 13 : 7;
  int dbase = (cb_idx == 13) ? 7 : 8;
  const float* cbk = (const float*)d_in[cb_idx];
  const float* d1w = (const float*)d_in[dbase + 0];
  const float* d1b = (const float*)d_in[dbase + 1];
  const float* d2w = (const float*)d_in[dbase + 2];
  const float* d2b = (const float*)d_in[dbase + 3];
  const float* d3w = (const float*)d_in[dbase + 4];
  const float* d3b = (const float*)d_in[dbase + 5];

  float* out = (float*)d_out;
  float* rec = out;                 // (2048,1,1024)
  float* cont_out = out + 2097152;  // (2048,12,16)
  float* quant_out = out + 2490368; // (2048,12,16)

  char* wsb = (char*)d_ws;
  double* q64 = (double*)(wsb + WSB_Q64);
  float* decoded = (float*)(wsb + WSB_Q64);  // overlap: q64 dead after k_vq2
  unsigned* qmax = (unsigned*)(wsb + WSB_QZ);
  unsigned long long* keys = (unsigned long long*)(wsb + WSB_KEYS);
  double* cch = (double*)(wsb + WSB_CCH);
  double* w1d = (double*)(wsb + WSB_W1D);
  double* w2d = (double*)(wsb + WSB_W2D);
  double* w3d = (double*)(wsb + WSB_W3D);
  double* b1d = (double*)(wsb + WSB_B1D);
  double* b2d = (double*)(wsb + WSB_B2D);
  double* b3d = (double*)(wsb + WSB_B3D);
  float* d1r = (float*)(wsb + WSB_D1R);
  float* d2r = (float*)(wsb + WSB_D2R);
  float* d3r = (float*)(wsb + WSB_D3R);
  _Float16* cb16 = (_Float16*)(wsb + WSB_CB16);
  _Float16* q16 = (_Float16*)(wsb + WSB_Q16);

  k_prep<<<32, 256, 0, stream>>>(w1, b1, w2, b2, w3, b3, cbk, d1w, d2w, d3w,
                                 cch, w1d, w2d, w3d, b1d, b2d, b3d,
                                 d1r, d2r, d3r, cb16);
  k_enc<<<256, 512, 0, stream>>>(x, w1d, w2d, w3d, b1d, b2d, b3d, cont_out,
                                 q64, q16, qmax);
  k_vq1<<<2048, 256, 0, stream>>>(q16, cb16, qmax, keys);
  k_vq2<<<2048, 256, 0, stream>>>(q16, cb16, qmax, q64, cbk, cch, keys);
  k_pre<<<256, 256, 0, stream>>>(cbk, d1r, d2r, d3r, d1b, d2b, d3b, decoded);
  k_gather<<<2048, 256, 0, stream>>>(keys, decoded, cbk, quant_out, rec);
}

// Round 20
// 110.437 us; speedup vs baseline: 1.4411x; 1.0670x over previous
//
#include <hip/hip_runtime.h>
#include <math.h>

// ---------------------------------------------------------------------------
// SphericalConvCodec. fp64 decision path (encoder + exact rescore) matches the
// fp64 numpy reference; VQ scan uses f16 MFMA (32x32x16), two barrier-free
// kernels reading the L2-resident codebook straight from global; decoder =
// decode-each-code-once + gather. Round 20: k_prep folded into k_enc (inline
// float->double weight staging, exact); k_enc red buffer halved to 48 KB via
// two-phase A/B reduction -> 2 blocks/CU (4 waves/SIMD, was 2).
// codebook = d_in[13] (dict-literal order puts it after decoder weights).
// ws layout (byte offsets):
#define WSB_Q64   0u         // 32768*12 double; decoded[8192][64] f32 (2MB)
                             //   overlaps AFTER k_vq2 (q64 dead by then)
#define WSB_QZ    3145728u   // qmax u32[32768] lives here
#define WSB_KEYS  4718592u   // 32768 u64        (262144 B)
#define WSB_CCH   4980736u   // 8192 double      (65536 B)
#define WSB_D1R   5075936u   // 1536 float [p][o][c]
#define WSB_D2R   5082080u   // 2048 float [k][o][c]
#define WSB_D3R   5090272u   // 64 float  [k][c]
#define WSB_CB16  5090528u   // 8192*16 _Float16, FRAGMENT-ORDERED [tile][half][col][8]
#define WSB_Q16   5352672u   // 32768*16 _Float16 (1048576 B)
#define DELTA 0.003f
#define SCALE46 70368744177664.0  // 2^46
#define WCAP 512

typedef _Float16 half8 __attribute__((ext_vector_type(8)));
typedef float f32x16 __attribute__((ext_vector_type(16)));

__device__ __forceinline__ float relu(float v) { return v > 0.f ? v : 0.f; }

// monotone float<->uint order transform (valid for all finite floats)
__device__ __forceinline__ unsigned okey(float s) {
  unsigned u = __float_as_uint(s);
  return u ^ ((u & 0x80000000u) ? 0xFFFFFFFFu : 0x80000000u);
}
__device__ __forceinline__ float unokey(unsigned k) {
  unsigned u = k ^ ((k & 0x80000000u) ? 0x80000000u : 0xFFFFFFFFu);
  return __uint_as_float(u);
}

// ---------------------------------------------------------------------------
// encoder, fp64, with prep folded in. Block = 512 = 8 waves, wave = (quarter
// qq, o-half oh); 2 window-sets per thread; weights converted float->double
// INLINE while staging to LDS (exact); conv chains identical to all passing
// rounds. Two-phase A/B reduction reuses one 48 KB red buffer -> total LDS
// ~77 KB -> 2 blocks/CU. Blocks 0-15 also build cch/cb16; block 16 repacks
// decoder weights; all blocks zero their qmax slice.
__global__ __launch_bounds__(512, 2) void k_enc(
    const float* __restrict__ x, const float* __restrict__ w1,
    const float* __restrict__ b1, const float* __restrict__ w2,
    const float* __restrict__ b2, const float* __restrict__ w3,
    const float* __restrict__ b3, const float* __restrict__ cbk,
    const float* __restrict__ d1w, const float* __restrict__ d2w,
    const float* __restrict__ d3w, float* __restrict__ cont_out,
    double* __restrict__ q64out, _Float16* __restrict__ q16out,
    unsigned* __restrict__ qmax, double* __restrict__ cch,
    _Float16* __restrict__ cb16, float* __restrict__ d1r,
    float* __restrict__ d2r, float* __restrict__ d3r) {
  __shared__ double w2s[2048];          // 16 KB
  __shared__ double w3s[1536];          // 12 KB
  __shared__ double w1s[64];
  __shared__ double b1s[16], b2s[32], b3s[12];
  __shared__ double red[8][64][12];     // 48 KB; total ~77 KB -> 2 blocks/CU

  int t = threadIdx.x;
  int gid0 = blockIdx.x * 512 + t;
  if (gid0 < 32768) qmax[gid0] = 0u;   // < okey(-3): any real score beats it

  // folded prep: blocks 0-15 build cch + fragment-ordered cb16
  if (blockIdx.x < 16) {
    int code = blockIdx.x * 512 + t;   // 0..8191
    double s = 0.0;
    half8 lo, hi;
#pragma unroll
    for (int d = 0; d < 12; d++) {
      float cf = cbk[code * 12 + d];
      double c = (double)cf;
      s = fma(c, c, s);
      if (d < 8) lo[d] = (_Float16)cf; else hi[d - 8] = (_Float16)cf;
    }
#pragma unroll
    for (int d = 4; d < 8; d++) hi[d] = (_Float16)0.f;
    cch[code] = 0.5 * s;
    int tile = code >> 5, col = code & 31;
    *(half8*)(cb16 + (size_t)(tile * 64 + col) * 8) = lo;        // half 0
    *(half8*)(cb16 + (size_t)(tile * 64 + 32 + col) * 8) = hi;   // half 1
  } else if (blockIdx.x == 16) {       // decoder weight repacks (for k_pre)
    for (int i = t; i < 1536; i += 512) {  // d1r[p][o][c] = d1w[c][o][p]
      int p = i / 384, r = i % 384, o = r / 12, c = r % 12;
      d1r[i] = d1w[c * 128 + o * 4 + p];
    }
    for (int i = t; i < 2048; i += 512) {  // d2r[k][o][c] = d2w[c][o][k]
      int k = i >> 9, o = (i >> 5) & 15, c = i & 31;
      d2r[i] = d2w[c * 64 + o * 4 + k];
    }
    for (int i = t; i < 64; i += 512) {    // d3r[k][c] = d3w[c][k]
      int k = i >> 4, c = i & 15;
      d3r[i] = d3w[c * 4 + k];
    }
  }

  // stage weights to LDS, converting float->double inline (exact)
  for (int i = t; i < 2048; i += 512) {    // w2s[k][o][c] = w2[o][c][k]
    int k = i >> 9, o = (i >> 4) & 31, c = i & 15;
    w2s[i] = (double)w2[o * 64 + c * 4 + k];
  }
  for (int i = t; i < 1536; i += 512) {    // w3s[q][j][o] = w3[j][o][q]
    int q = i / 384, r = i % 384, j = r >> 5, o = r & 31;
    w3s[i] = (double)w3[j * 128 + o * 4 + q];
  }
  if (t < 64) w1s[t] = (double)w1[t];
  else if (t >= 64 && t < 80) b1s[t - 64] = (double)b1[t - 64];
  else if (t >= 80 && t < 112) b2s[t - 80] = (double)b2[t - 80];
  else if (t >= 112 && t < 124) b3s[t - 112] = (double)b3[t - 112];
  __syncthreads();

  int w = t >> 6, lane = t & 63;
  int qq = w & 3, oh = w >> 2;
  int winA = blockIdx.x * 64 + lane;    // grid 256 -> sets 0..16383
  int winB = winA + 16384;
  const float* xbA = x + (winA >> 4) * 1024 + (winA & 15) * 64 + qq * 16;
  const float* xbB = x + (winB >> 4) * 1024 + (winB & 15) * 64 + qq * 16;

  double h2A[16], h2B[16];
#pragma unroll
  for (int o = 0; o < 16; o++) { h2A[o] = b2s[oh * 16 + o]; h2B[o] = h2A[o]; }

#pragma unroll 1
  for (int k = 0; k < 4; k++) {
    float4 xvA = *reinterpret_cast<const float4*>(xbA + 4 * k);
    float4 xvB = *reinterpret_cast<const float4*>(xbB + 4 * k);
    double xA0 = (double)xvA.x, xA1 = (double)xvA.y;
    double xA2 = (double)xvA.z, xA3 = (double)xvA.w;
    double xB0 = (double)xvB.x, xB1 = (double)xvB.y;
    double xB2 = (double)xvB.z, xB3 = (double)xvB.w;
    double h1A[16], h1B[16];
#pragma unroll
    for (int c = 0; c < 16; c++) {
      double2 wa = *(const double2*)(w1s + 4 * c);
      double2 wb = *(const double2*)(w1s + 4 * c + 2);
      double bb = b1s[c];
      double sA = bb, sB = bb;
      sA = fma(xA0, wa.x, sA); sB = fma(xB0, wa.x, sB);
      sA = fma(xA1, wa.y, sA); sB = fma(xB1, wa.y, sB);
      sA = fma(xA2, wb.x, sA); sB = fma(xB2, wb.x, sB);
      sA = fma(xA3, wb.y, sA); sB = fma(xB3, wb.y, sB);
      h1A[c] = sA > 0.0 ? sA : 0.0;
      h1B[c] = sB > 0.0 ? sB : 0.0;
    }
    const double* w2k = w2s + k * 512 + oh * 256;
#pragma unroll
    for (int o = 0; o < 16; o++) {
      const double* wp = w2k + o * 16;
      double sA = h2A[o], sB = h2B[o];
#pragma unroll
      for (int c = 0; c < 16; c += 2) {
        double2 wv = *(const double2*)(wp + c);
        sA = fma(h1A[c], wv.x, sA); sA = fma(h1A[c + 1], wv.y, sA);
        sB = fma(h1B[c], wv.x, sB); sB = fma(h1B[c + 1], wv.y, sB);
      }
      h2A[o] = sA; h2B[o] = sB;
    }
  }
#pragma unroll
  for (int o = 0; o < 16; o++) {
    h2A[o] = h2A[o] > 0.0 ? h2A[o] : 0.0;
    h2B[o] = h2B[o] > 0.0 ? h2B[o] : 0.0;
  }

  const double* w3q = w3s + qq * 384 + oh * 16;

  // ---- phase A: partials, reduce, emit (set A) ----
#pragma unroll
  for (int j = 0; j < 12; j++) {
    const double* wp = w3q + j * 32;
    double sA = 0.0;
#pragma unroll
    for (int o = 0; o < 16; o += 2) {
      double2 wv = *(const double2*)(wp + o);
      sA = fma(h2A[o], wv.x, sA); sA = fma(h2A[o + 1], wv.y, sA);
    }
    red[w][lane][j] = sA;
  }
  __syncthreads();
  if (w == 0) {
    int win = blockIdx.x * 64 + lane;
    int n = win >> 4, l = win & 15;
    double cont[12], ss = 0.0;
#pragma unroll
    for (int j = 0; j < 12; j++) {
      double v = b3s[j] +
          (((red[0][lane][j] + red[1][lane][j]) +
            (red[2][lane][j] + red[3][lane][j])) +
           ((red[4][lane][j] + red[5][lane][j]) +
            (red[6][lane][j] + red[7][lane][j])));
      cont[j] = v;
      ss = fma(v, v, ss);
    }
    double nrm = sqrt(ss);
    if (nrm < 1e-12) nrm = 1e-12;
    half8 lo, hi;
#pragma unroll
    for (int j = 0; j < 12; j++) {
      double qv = cont[j] / nrm;
      float qf = (float)qv;
      cont_out[n * 192 + j * 16 + l] = qf;
      q64out[(size_t)win * 12 + j] = qv;
      if (j < 8) lo[j] = (_Float16)qf; else hi[j - 8] = (_Float16)qf;
    }
#pragma unroll
    for (int j = 4; j < 8; j++) hi[j] = (_Float16)0.f;
    *(half8*)(q16out + (size_t)win * 16) = lo;
    *(half8*)(q16out + (size_t)win * 16 + 8) = hi;
  }
  __syncthreads();

  // ---- phase B: partials, reduce, emit (set B) ----
#pragma unroll
  for (int j = 0; j < 12; j++) {
    const double* wp = w3q + j * 32;
    double sB = 0.0;
#pragma unroll
    for (int o = 0; o < 16; o += 2) {
      double2 wv = *(const double2*)(wp + o);
      sB = fma(h2B[o], wv.x, sB); sB = fma(h2B[o + 1], wv.y, sB);
    }
    red[w][lane][j] = sB;
  }
  __syncthreads();
  if (w == 0) {
    int win = blockIdx.x * 64 + lane + 16384;
    int n = win >> 4, l = win & 15;
    double cont[12], ss = 0.0;
#pragma unroll
    for (int j = 0; j < 12; j++) {
      double v = b3s[j] +
          (((red[0][lane][j] + red[1][lane][j]) +
            (red[2][lane][j] + red[3][lane][j])) +
           ((red[4][lane][j] + red[5][lane][j]) +
            (red[6][lane][j] + red[7][lane][j])));
      cont[j] = v;
      ss = fma(v, v, ss);
    }
    double nrm = sqrt(ss);
    if (nrm < 1e-12) nrm = 1e-12;
    half8 lo, hi;
#pragma unroll
    for (int j = 0; j < 12; j++) {
      double qv = cont[j] / nrm;
      float qf = (float)qv;
      cont_out[n * 192 + j * 16 + l] = qf;
      q64out[(size_t)win * 12 + j] = qv;
      if (j < 8) lo[j] = (_Float16)qf; else hi[j - 8] = (_Float16)qf;
    }
#pragma unroll
    for (int j = 4; j < 8; j++) hi[j] = (_Float16)0.f;
    *(half8*)(q16out + (size_t)win * 16) = lo;
    *(half8*)(q16out + (size_t)win * 16 + 8) = hi;
  }
}

// ---------------------------------------------------------------------------
// VQ pass 1 (unchanged): per-query GLOBAL f16 max via distributed atomicMax.
// Barrier-free, depth-4 register prefetch from global; cq==0 blocks zero keys.
// D layout: col=lane&31, row=(reg&3)+8*(reg>>2)+4*(lane>>5)  [m74/m101]
__global__ __launch_bounds__(256, 4) void k_vq1(
    const _Float16* __restrict__ q16, const _Float16* __restrict__ cbf,
    unsigned* __restrict__ qmax, unsigned long long* __restrict__ keys) {
  int t = threadIdx.x;
  int w = t >> 6, lane = t & 63;
  int half = lane >> 5, col = lane & 31;
  int qg = blockIdx.x >> 3;  // 256 query groups of 128
  int cq = blockIdx.x & 7;   // 8 code chunks of 1024 (32 tiles)
  if (cq == 0 && t < 128) keys[qg * 128 + t] = 0ull;
  int qbase = qg * 128 + w * 32;
  const _Float16* bp = cbf + (size_t)cq * 32 * 64 * 8;

  half8 a = *(const half8*)(q16 + (size_t)(qbase + col) * 16 + half * 8);
  f32x16 z = {0.f, 0.f, 0.f, 0.f, 0.f, 0.f, 0.f, 0.f,
              0.f, 0.f, 0.f, 0.f, 0.f, 0.f, 0.f, 0.f};

  half8 b0 = *(const half8*)(bp + (0 * 64 + lane) * 8);
  half8 b1 = *(const half8*)(bp + (1 * 64 + lane) * 8);
  half8 b2 = *(const half8*)(bp + (2 * 64 + lane) * 8);
  half8 b3 = *(const half8*)(bp + (3 * 64 + lane) * 8);

  float mx[16];
#pragma unroll
  for (int r = 0; r < 16; r++) mx[r] = -3.f;

  f32x16 dp = __builtin_amdgcn_mfma_f32_32x32x16_f16(a, b0, z, 0, 0, 0);
  b0 = b1; b1 = b2; b2 = b3;
  b3 = *(const half8*)(bp + (4 * 64 + lane) * 8);

#pragma unroll 4
  for (int tt = 1; tt < 32; tt++) {
    f32x16 d = __builtin_amdgcn_mfma_f32_32x32x16_f16(a, b0, z, 0, 0, 0);
    b0 = b1; b1 = b2; b2 = b3;
    if (tt + 4 < 32) b3 = *(const half8*)(bp + ((tt + 4) * 64 + lane) * 8);
#pragma unroll
    for (int r = 0; r < 16; r++) mx[r] = fmaxf(mx[r], dp[r]);
    dp = d;
  }
#pragma unroll
  for (int r = 0; r < 16; r++) mx[r] = fmaxf(mx[r], dp[r]);

  // reduce across 32 columns (xor masks <=16 stay within each 32-half)
#pragma unroll
  for (int m = 1; m <= 16; m <<= 1) {
#pragma unroll
    for (int r = 0; r < 16; r++) mx[r] = fmaxf(mx[r], __shfl_xor(mx[r], m));
  }
  // lane col==r (one per half) publishes row max; addresses all distinct
#pragma unroll
  for (int r = 0; r < 16; r++) {
    if (col == r) {
      unsigned row = (r & 3) + 8 * (r >> 2) + 4 * half;
      atomicMax(&qmax[qbase + row], okey(mx[r]));
    }
  }
}

// ---------------------------------------------------------------------------
// VQ pass 2 (unchanged): barrier-free pipelined re-scan; candidates >= max -
// DELTA pushed to a per-wave LDS list; fp64 rescore at end (fma chain/key/
// tie-break identical to all passing rounds).
__global__ __launch_bounds__(256, 3) void k_vq2(
    const _Float16* __restrict__ q16, const _Float16* __restrict__ cbf,
    const unsigned* __restrict__ qmax, const double* __restrict__ q64,
    const float* __restrict__ cbk, const double* __restrict__ cchalf,
    unsigned long long* __restrict__ keys) {
  __shared__ unsigned wlist[4][WCAP];  // 8 KB
  __shared__ int wcnt[4];
  int t = threadIdx.x;
  int w = t >> 6, lane = t & 63;
  int half = lane >> 5, col = lane & 31;
  if (lane == 0) wcnt[w] = 0;   // per-wave, no block barrier needed
  int qg = blockIdx.x >> 3;
  int cq = blockIdx.x & 7;
  int qbase = qg * 128 + w * 32;
  int cbase = cq * 1024;
  const _Float16* bp = cbf + (size_t)cq * 32 * 64 * 8;

  half8 a = *(const half8*)(q16 + (size_t)(qbase + col) * 16 + half * 8);
  f32x16 z = {0.f, 0.f, 0.f, 0.f, 0.f, 0.f, 0.f, 0.f,
              0.f, 0.f, 0.f, 0.f, 0.f, 0.f, 0.f, 0.f};

  float thr[16];
#pragma unroll
  for (int r = 0; r < 16; r++) {
    unsigned row = (r & 3) + 8 * (r >> 2) + 4 * half;
    thr[r] = unokey(qmax[qbase + row]) - DELTA;
  }

  half8 b0 = *(const half8*)(bp + (0 * 64 + lane) * 8);
  half8 b1 = *(const half8*)(bp + (1 * 64 + lane) * 8);
  half8 b2 = *(const half8*)(bp + (2 * 64 + lane) * 8);
  half8 b3 = *(const half8*)(bp + (3 * 64 + lane) * 8);

#define CONSUME(dv, ttv)                                                      \
  {                                                                           \
    _Pragma("unroll") for (int r = 0; r < 16; r++) {                          \
      if (dv[r] >= thr[r]) {                                                  \
        int slot = atomicAdd(&wcnt[w], 1);                                    \
        unsigned row = (r & 3) + 8 * (r >> 2) + 4 * half;                     \
        unsigned enc = ((unsigned)(qbase + row) << 13) |                      \
                       (unsigned)(cbase + (ttv)*32 + col);                    \
        if (slot < WCAP) wlist[w][slot] = enc;                                \
      }                                                                       \
    }                                                                         \
  }

  f32x16 dp = __builtin_amdgcn_mfma_f32_32x32x16_f16(a, b0, z, 0, 0, 0);
  b0 = b1; b1 = b2; b2 = b3;
  b3 = *(const half8*)(bp + (4 * 64 + lane) * 8);

#pragma unroll 4
  for (int tt = 1; tt < 32; tt++) {
    f32x16 d = __builtin_amdgcn_mfma_f32_32x32x16_f16(a, b0, z, 0, 0, 0);
    b0 = b1; b1 = b2; b2 = b3;
    if (tt + 4 < 32) b3 = *(const half8*)(bp + ((tt + 4) * 64 + lane) * 8);
    CONSUME(dp, tt - 1);
    dp = d;
  }
  CONSUME(dp, 31);
#undef CONSUME

  // rescore this wave's candidates exactly in fp64 (chain matches passing)
  int n = wcnt[w];
  if (n > WCAP) n = WCAP;
  for (int i = lane; i < n; i += 64) {
    unsigned e = wlist[w][i];
    int q = e >> 13, c = e & 8191;
    const double* qp = q64 + (size_t)q * 12;
    const float* cp = cbk + c * 12;
    double s = 0.0;
#pragma unroll
    for (int dd = 0; dd < 12; dd++) s = fma(qp[dd], (double)cp[dd], s);
    unsigned long long ek =
        (unsigned long long)((s - cchalf[c] + 2.0) * SCALE46);
    atomicMax(&keys[q], (ek << 16) | (unsigned)(8191 - c));
  }
}

// ---------------------------------------------------------------------------
// k_pre (unchanged): decode ALL 8192 codebook rows once -> decoded[8192][64].
// Thread = (code, p2, kh): 65536 threads, grid 256. Weights in LDS. fp32 fma
// chains identical to the passing k_dec -> bit-identical rec values.
__global__ __launch_bounds__(256) void k_pre(
    const float* __restrict__ cbk, const float* __restrict__ d1r,
    const float* __restrict__ d2r, const float* __restrict__ d3r,
    const float* __restrict__ d1b, const float* __restrict__ d2b,
    const float* __restrict__ d3b, float* __restrict__ decoded) {
  __shared__ float w1s[1536], w2s[2048], w3s[64];
  __shared__ float b1s[32], b2s_[16];
  int t = threadIdx.x;
  for (int i = t; i < 1536; i += 256) w1s[i] = d1r[i];
  for (int i = t; i < 2048; i += 256) w2s[i] = d2r[i];
  if (t < 64) w3s[t] = d3r[t];
  else if (t >= 64 && t < 96) b1s[t - 64] = d1b[t - 64];
  else if (t >= 96 && t < 112) b2s_[t - 96] = d2b[t - 96];
  __syncthreads();

  int code = blockIdx.x * 32 + (t & 31);
  int p2 = (t >> 5) & 3;
  int kh = t >> 7;
  const float* cp = cbk + code * 12;
  float4 q0 = *(const float4*)(cp);
  float4 q1 = *(const float4*)(cp + 4);
  float4 q2 = *(const float4*)(cp + 8);

  const float* d1p = w1s + p2 * 384;
  float y1[32];
#pragma unroll
  for (int o = 0; o < 32; o++) {
    const float* wp = d1p + o * 12;
    float s = b1s[o];
    s = fmaf(q0.x, wp[0], s); s = fmaf(q0.y, wp[1], s);
    s = fmaf(q0.z, wp[2], s); s = fmaf(q0.w, wp[3], s);
    s = fmaf(q1.x, wp[4], s); s = fmaf(q1.y, wp[5], s);
    s = fmaf(q1.z, wp[6], s); s = fmaf(q1.w, wp[7], s);
    s = fmaf(q2.x, wp[8], s); s = fmaf(q2.y, wp[9], s);
    s = fmaf(q2.z, wp[10], s); s = fmaf(q2.w, wp[11], s);
    y1[o] = relu(s);
  }

  float d3bias = d3b[0];
#pragma unroll
  for (int kk2 = 0; kk2 < 2; kk2++) {
    int k = kh * 2 + kk2;
    const float* d2k = w2s + k * 512;
    float y2[16];
#pragma unroll
    for (int o = 0; o < 16; o++) {
      const float* wp = d2k + o * 32;
      float s = b2s_[o];
#pragma unroll
      for (int c = 0; c < 32; c += 4) {
        s = fmaf(y1[c + 0], wp[c + 0], s); s = fmaf(y1[c + 1], wp[c + 1], s);
        s = fmaf(y1[c + 2], wp[c + 2], s); s = fmaf(y1[c + 3], wp[c + 3], s);
      }
      y2[o] = relu(s);
    }
    float ov[4];
#pragma unroll
    for (int kk = 0; kk < 4; kk++) {
      const float* wp = w3s + kk * 16;
      float s = d3bias;
#pragma unroll
      for (int g = 0; g < 16; g += 4) {
        s = fmaf(y2[g + 0], wp[g + 0], s); s = fmaf(y2[g + 1], wp[g + 1], s);
        s = fmaf(y2[g + 2], wp[g + 2], s); s = fmaf(y2[g + 3], wp[g + 3], s);
      }
      ov[kk] = s;
    }
    *reinterpret_cast<float4*>(decoded + (size_t)code * 64 + p2 * 16 + k * 4) =
        make_float4(ov[0], ov[1], ov[2], ov[3]);
  }
}

// ---------------------------------------------------------------------------
// k_gather (unchanged): rec[win] = decoded[key[win]]; quant_out from codebook.
__global__ __launch_bounds__(256) void k_gather(
    const unsigned long long* __restrict__ keys,
    const float* __restrict__ decoded, const float* __restrict__ cbk,
    float* __restrict__ quant_out, float* __restrict__ rec) {
  int g = blockIdx.x * 256 + threadIdx.x;  // grid 2048 -> 524288
  int win = g >> 4, i = g & 15;
  int gidx = 8191 - (int)(keys[win] & 0xFFFFull);
  float4 v = ((const float4*)(decoded + (size_t)gidx * 64))[i];
  ((float4*)(rec + (size_t)win * 64))[i] = v;
  if (i < 12) {
    int n = win >> 4, l = win & 15;
    quant_out[n * 192 + i * 16 + l] = cbk[gidx * 12 + i];
  }
}

// ---------------------------------------------------------------------------
extern "C" void kernel_launch(void* const* d_in, const int* in_sizes, int n_in,
                              void* d_out, int out_size, void* d_ws,
                              size_t ws_size, hipStream_t stream) {
  const float* x  = (const float*)d_in[0];
  const float* w1 = (const float*)d_in[1];
  const float* b1 = (const float*)d_in[2];
  const float* w2 = (const float*)d_in[3];
  const float* b2 = (const float*)d_in[4];
  const float* w3 = (const float*)d_in[5];
  const float* b3 = (const float*)d_in[6];
  int cb_idx = (in_sizes[13] == 98304) ? 13 : 7;
  int dbase = (cb_idx == 13) ? 7 : 8;
  const float* cbk = (const float*)d_in[cb_idx];
  const float* d1w = (const float*)d_in[dbase + 0];
  const float* d1b = (const float*)d_in[dbase + 1];
  const float* d2w = (const float*)d_in[dbase + 2];
  const float* d2b = (const float*)d_in[dbase + 3];
  const float* d3w = (const float*)d_in[dbase + 4];
  const float* d3b = (const float*)d_in[dbase + 5];

  float* out = (float*)d_out;
  float* rec = out;                 // (2048,1,1024)
  float* cont_out = out + 2097152;  // (2048,12,16)
  float* quant_out = out + 2490368; // (2048,12,16)

  char* wsb = (char*)d_ws;
  double* q64 = (double*)(wsb + WSB_Q64);
  float* decoded = (float*)(wsb + WSB_Q64);  // overlap: q64 dead after k_vq2
  unsigned* qmax = (unsigned*)(wsb + WSB_QZ);
  unsigned long long* keys = (unsigned long long*)(wsb + WSB_KEYS);
  double* cch = (double*)(wsb + WSB_CCH);
  float* d1r = (float*)(wsb + WSB_D1R);
  float* d2r = (float*)(wsb + WSB_D2R);
  float* d3r = (float*)(wsb + WSB_D3R);
  _Float16* cb16 = (_Float16*)(wsb + WSB_CB16);
  _Float16* q16 = (_Float16*)(wsb + WSB_Q16);

  k_enc<<<256, 512, 0, stream>>>(x, w1, b1, w2, b2, w3, b3, cbk, d1w, d2w,
                                 d3w, cont_out, q64, q16, qmax, cch, cb16,
                                 d1r, d2r, d3r);
  k_vq1<<<2048, 256, 0, stream>>>(q16, cb16, qmax, keys);
  k_vq2<<<2048, 256, 0, stream>>>(q16, cb16, qmax, q64, cbk, cch, keys);
  k_pre<<<256, 256, 0, stream>>>(cbk, d1r, d2r, d3r, d1b, d2b, d3b, decoded);
  k_gather<<<2048, 256, 0, stream>>>(keys, decoded, cbk, quant_out, rec);
}

// Round 22
// 109.734 us; speedup vs baseline: 1.4503x; 1.0064x over previous
//
#include <hip/hip_runtime.h>
#include <math.h>

// ---------------------------------------------------------------------------
// SphericalConvCodec. fp64 decision path (encoder + exact rescore) matches the
// fp64 numpy reference; VQ scan uses f16 MFMA (32x32x16), two barrier-free
// kernels reading the L2-resident codebook straight from global; decoder =
// decode-each-code-once + gather. Round 22: revert to the verified round-20
// configuration (round 21's single-pass VQ filter overflowed: per-lane
// running max over 32-code sequences admits ~4k candidates/wave >> cap).
// codebook = d_in[13] (dict-literal order puts it after decoder weights).
// ws layout (byte offsets):
#define WSB_Q64   0u         // 32768*12 double; decoded[8192][64] f32 (2MB)
                             //   overlaps AFTER k_vq2 (q64 dead by then)
#define WSB_QZ    3145728u   // qmax u32[32768] lives here
#define WSB_KEYS  4718592u   // 32768 u64        (262144 B)
#define WSB_CCH   4980736u   // 8192 double      (65536 B)
#define WSB_D1R   5075936u   // 1536 float [p][o][c]
#define WSB_D2R   5082080u   // 2048 float [k][o][c]
#define WSB_D3R   5090272u   // 64 float  [k][c]
#define WSB_CB16  5090528u   // 8192*16 _Float16, FRAGMENT-ORDERED [tile][half][col][8]
#define WSB_Q16   5352672u   // 32768*16 _Float16 (1048576 B)
#define DELTA 0.003f
#define SCALE46 70368744177664.0  // 2^46
#define WCAP 512

typedef _Float16 half8 __attribute__((ext_vector_type(8)));
typedef float f32x16 __attribute__((ext_vector_type(16)));

__device__ __forceinline__ float relu(float v) { return v > 0.f ? v : 0.f; }

// monotone float<->uint order transform (valid for all finite floats)
__device__ __forceinline__ unsigned okey(float s) {
  unsigned u = __float_as_uint(s);
  return u ^ ((u & 0x80000000u) ? 0xFFFFFFFFu : 0x80000000u);
}
__device__ __forceinline__ float unokey(unsigned k) {
  unsigned u = k ^ ((k & 0x80000000u) ? 0x80000000u : 0xFFFFFFFFu);
  return __uint_as_float(u);
}

// ---------------------------------------------------------------------------
// encoder, fp64, with prep folded in. Block = 512 = 8 waves, wave = (quarter
// qq, o-half oh); 2 window-sets per thread; weights converted float->double
// INLINE while staging to LDS (exact); conv chains identical to all passing
// rounds. Two-phase A/B reduction reuses one 48 KB red buffer -> total LDS
// ~77 KB -> 2 blocks/CU. Blocks 0-15 also build cch/cb16; block 16 repacks
// decoder weights; all blocks zero their qmax slice.
__global__ __launch_bounds__(512, 2) void k_enc(
    const float* __restrict__ x, const float* __restrict__ w1,
    const float* __restrict__ b1, const float* __restrict__ w2,
    const float* __restrict__ b2, const float* __restrict__ w3,
    const float* __restrict__ b3, const float* __restrict__ cbk,
    const float* __restrict__ d1w, const float* __restrict__ d2w,
    const float* __restrict__ d3w, float* __restrict__ cont_out,
    double* __restrict__ q64out, _Float16* __restrict__ q16out,
    unsigned* __restrict__ qmax, double* __restrict__ cch,
    _Float16* __restrict__ cb16, float* __restrict__ d1r,
    float* __restrict__ d2r, float* __restrict__ d3r) {
  __shared__ double w2s[2048];          // 16 KB
  __shared__ double w3s[1536];          // 12 KB
  __shared__ double w1s[64];
  __shared__ double b1s[16], b2s[32], b3s[12];
  __shared__ double red[8][64][12];     // 48 KB; total ~77 KB -> 2 blocks/CU

  int t = threadIdx.x;
  int gid0 = blockIdx.x * 512 + t;
  if (gid0 < 32768) qmax[gid0] = 0u;   // < okey(-3): any real score beats it

  // folded prep: blocks 0-15 build cch + fragment-ordered cb16
  if (blockIdx.x < 16) {
    int code = blockIdx.x * 512 + t;   // 0..8191
    double s = 0.0;
    half8 lo, hi;
#pragma unroll
    for (int d = 0; d < 12; d++) {
      float cf = cbk[code * 12 + d];
      double c = (double)cf;
      s = fma(c, c, s);
      if (d < 8) lo[d] = (_Float16)cf; else hi[d - 8] = (_Float16)cf;
    }
#pragma unroll
    for (int d = 4; d < 8; d++) hi[d] = (_Float16)0.f;
    cch[code] = 0.5 * s;
    int tile = code >> 5, col = code & 31;
    *(half8*)(cb16 + (size_t)(tile * 64 + col) * 8) = lo;        // half 0
    *(half8*)(cb16 + (size_t)(tile * 64 + 32 + col) * 8) = hi;   // half 1
  } else if (blockIdx.x == 16) {       // decoder weight repacks (for k_pre)
    for (int i = t; i < 1536; i += 512) {  // d1r[p][o][c] = d1w[c][o][p]
      int p = i / 384, r = i % 384, o = r / 12, c = r % 12;
      d1r[i] = d1w[c * 128 + o * 4 + p];
    }
    for (int i = t; i < 2048; i += 512) {  // d2r[k][o][c] = d2w[c][o][k]
      int k = i >> 9, o = (i >> 5) & 15, c = i & 31;
      d2r[i] = d2w[c * 64 + o * 4 + k];
    }
    for (int i = t; i < 64; i += 512) {    // d3r[k][c] = d3w[c][k]
      int k = i >> 4, c = i & 15;
      d3r[i] = d3w[c * 4 + k];
    }
  }

  // stage weights to LDS, converting float->double inline (exact)
  for (int i = t; i < 2048; i += 512) {    // w2s[k][o][c] = w2[o][c][k]
    int k = i >> 9, o = (i >> 4) & 31, c = i & 15;
    w2s[i] = (double)w2[o * 64 + c * 4 + k];
  }
  for (int i = t; i < 1536; i += 512) {    // w3s[q][j][o] = w3[j][o][q]
    int q = i / 384, r = i % 384, j = r >> 5, o = r & 31;
    w3s[i] = (double)w3[j * 128 + o * 4 + q];
  }
  if (t < 64) w1s[t] = (double)w1[t];
  else if (t >= 64 && t < 80) b1s[t - 64] = (double)b1[t - 64];
  else if (t >= 80 && t < 112) b2s[t - 80] = (double)b2[t - 80];
  else if (t >= 112 && t < 124) b3s[t - 112] = (double)b3[t - 112];
  __syncthreads();

  int w = t >> 6, lane = t & 63;
  int qq = w & 3, oh = w >> 2;
  int winA = blockIdx.x * 64 + lane;    // grid 256 -> sets 0..16383
  int winB = winA + 16384;
  const float* xbA = x + (winA >> 4) * 1024 + (winA & 15) * 64 + qq * 16;
  const float* xbB = x + (winB >> 4) * 1024 + (winB & 15) * 64 + qq * 16;

  double h2A[16], h2B[16];
#pragma unroll
  for (int o = 0; o < 16; o++) { h2A[o] = b2s[oh * 16 + o]; h2B[o] = h2A[o]; }

#pragma unroll 1
  for (int k = 0; k < 4; k++) {
    float4 xvA = *reinterpret_cast<const float4*>(xbA + 4 * k);
    float4 xvB = *reinterpret_cast<const float4*>(xbB + 4 * k);
    double xA0 = (double)xvA.x, xA1 = (double)xvA.y;
    double xA2 = (double)xvA.z, xA3 = (double)xvA.w;
    double xB0 = (double)xvB.x, xB1 = (double)xvB.y;
    double xB2 = (double)xvB.z, xB3 = (double)xvB.w;
    double h1A[16], h1B[16];
#pragma unroll
    for (int c = 0; c < 16; c++) {
      double2 wa = *(const double2*)(w1s + 4 * c);
      double2 wb = *(const double2*)(w1s + 4 * c + 2);
      double bb = b1s[c];
      double sA = bb, sB = bb;
      sA = fma(xA0, wa.x, sA); sB = fma(xB0, wa.x, sB);
      sA = fma(xA1, wa.y, sA); sB = fma(xB1, wa.y, sB);
      sA = fma(xA2, wb.x, sA); sB = fma(xB2, wb.x, sB);
      sA = fma(xA3, wb.y, sA); sB = fma(xB3, wb.y, sB);
      h1A[c] = sA > 0.0 ? sA : 0.0;
      h1B[c] = sB > 0.0 ? sB : 0.0;
    }
    const double* w2k = w2s + k * 512 + oh * 256;
#pragma unroll
    for (int o = 0; o < 16; o++) {
      const double* wp = w2k + o * 16;
      double sA = h2A[o], sB = h2B[o];
#pragma unroll
      for (int c = 0; c < 16; c += 2) {
        double2 wv = *(const double2*)(wp + c);
        sA = fma(h1A[c], wv.x, sA); sA = fma(h1A[c + 1], wv.y, sA);
        sB = fma(h1B[c], wv.x, sB); sB = fma(h1B[c + 1], wv.y, sB);
      }
      h2A[o] = sA; h2B[o] = sB;
    }
  }
#pragma unroll
  for (int o = 0; o < 16; o++) {
    h2A[o] = h2A[o] > 0.0 ? h2A[o] : 0.0;
    h2B[o] = h2B[o] > 0.0 ? h2B[o] : 0.0;
  }

  const double* w3q = w3s + qq * 384 + oh * 16;

  // ---- phase A: partials, reduce, emit (set A) ----
#pragma unroll
  for (int j = 0; j < 12; j++) {
    const double* wp = w3q + j * 32;
    double sA = 0.0;
#pragma unroll
    for (int o = 0; o < 16; o += 2) {
      double2 wv = *(const double2*)(wp + o);
      sA = fma(h2A[o], wv.x, sA); sA = fma(h2A[o + 1], wv.y, sA);
    }
    red[w][lane][j] = sA;
  }
  __syncthreads();
  if (w == 0) {
    int win = blockIdx.x * 64 + lane;
    int n = win >> 4, l = win & 15;
    double cont[12], ss = 0.0;
#pragma unroll
    for (int j = 0; j < 12; j++) {
      double v = b3s[j] +
          (((red[0][lane][j] + red[1][lane][j]) +
            (red[2][lane][j] + red[3][lane][j])) +
           ((red[4][lane][j] + red[5][lane][j]) +
            (red[6][lane][j] + red[7][lane][j])));
      cont[j] = v;
      ss = fma(v, v, ss);
    }
    double nrm = sqrt(ss);
    if (nrm < 1e-12) nrm = 1e-12;
    half8 lo, hi;
#pragma unroll
    for (int j = 0; j < 12; j++) {
      double qv = cont[j] / nrm;
      float qf = (float)qv;
      cont_out[n * 192 + j * 16 + l] = qf;
      q64out[(size_t)win * 12 + j] = qv;
      if (j < 8) lo[j] = (_Float16)qf; else hi[j - 8] = (_Float16)qf;
    }
#pragma unroll
    for (int j = 4; j < 8; j++) hi[j] = (_Float16)0.f;
    *(half8*)(q16out + (size_t)win * 16) = lo;
    *(half8*)(q16out + (size_t)win * 16 + 8) = hi;
  }
  __syncthreads();

  // ---- phase B: partials, reduce, emit (set B) ----
#pragma unroll
  for (int j = 0; j < 12; j++) {
    const double* wp = w3q + j * 32;
    double sB = 0.0;
#pragma unroll
    for (int o = 0; o < 16; o += 2) {
      double2 wv = *(const double2*)(wp + o);
      sB = fma(h2B[o], wv.x, sB); sB = fma(h2B[o + 1], wv.y, sB);
    }
    red[w][lane][j] = sB;
  }
  __syncthreads();
  if (w == 0) {
    int win = blockIdx.x * 64 + lane + 16384;
    int n = win >> 4, l = win & 15;
    double cont[12], ss = 0.0;
#pragma unroll
    for (int j = 0; j < 12; j++) {
      double v = b3s[j] +
          (((red[0][lane][j] + red[1][lane][j]) +
            (red[2][lane][j] + red[3][lane][j])) +
           ((red[4][lane][j] + red[5][lane][j]) +
            (red[6][lane][j] + red[7][lane][j])));
      cont[j] = v;
      ss = fma(v, v, ss);
    }
    double nrm = sqrt(ss);
    if (nrm < 1e-12) nrm = 1e-12;
    half8 lo, hi;
#pragma unroll
    for (int j = 0; j < 12; j++) {
      double qv = cont[j] / nrm;
      float qf = (float)qv;
      cont_out[n * 192 + j * 16 + l] = qf;
      q64out[(size_t)win * 12 + j] = qv;
      if (j < 8) lo[j] = (_Float16)qf; else hi[j - 8] = (_Float16)qf;
    }
#pragma unroll
    for (int j = 4; j < 8; j++) hi[j] = (_Float16)0.f;
    *(half8*)(q16out + (size_t)win * 16) = lo;
    *(half8*)(q16out + (size_t)win * 16 + 8) = hi;
  }
}

// ---------------------------------------------------------------------------
// VQ pass 1: per-query GLOBAL f16 max via distributed atomicMax. Barrier-free,
// depth-4 register prefetch from global; cq==0 blocks zero keys.
// D layout: col=lane&31, row=(reg&3)+8*(reg>>2)+4*(lane>>5)  [m74/m101]
__global__ __launch_bounds__(256, 4) void k_vq1(
    const _Float16* __restrict__ q16, const _Float16* __restrict__ cbf,
    unsigned* __restrict__ qmax, unsigned long long* __restrict__ keys) {
  int t = threadIdx.x;
  int w = t >> 6, lane = t & 63;
  int half = lane >> 5, col = lane & 31;
  int qg = blockIdx.x >> 3;  // 256 query groups of 128
  int cq = blockIdx.x & 7;   // 8 code chunks of 1024 (32 tiles)
  if (cq == 0 && t < 128) keys[qg * 128 + t] = 0ull;
  int qbase = qg * 128 + w * 32;
  const _Float16* bp = cbf + (size_t)cq * 32 * 64 * 8;

  half8 a = *(const half8*)(q16 + (size_t)(qbase + col) * 16 + half * 8);
  f32x16 z = {0.f, 0.f, 0.f, 0.f, 0.f, 0.f, 0.f, 0.f,
              0.f, 0.f, 0.f, 0.f, 0.f, 0.f, 0.f, 0.f};

  half8 b0 = *(const half8*)(bp + (0 * 64 + lane) * 8);
  half8 b1 = *(const half8*)(bp + (1 * 64 + lane) * 8);
  half8 b2 = *(const half8*)(bp + (2 * 64 + lane) * 8);
  half8 b3 = *(const half8*)(bp + (3 * 64 + lane) * 8);

  float mx[16];
#pragma unroll
  for (int r = 0; r < 16; r++) mx[r] = -3.f;

  f32x16 dp = __builtin_amdgcn_mfma_f32_32x32x16_f16(a, b0, z, 0, 0, 0);
  b0 = b1; b1 = b2; b2 = b3;
  b3 = *(const half8*)(bp + (4 * 64 + lane) * 8);

#pragma unroll 4
  for (int tt = 1; tt < 32; tt++) {
    f32x16 d = __builtin_amdgcn_mfma_f32_32x32x16_f16(a, b0, z, 0, 0, 0);
    b0 = b1; b1 = b2; b2 = b3;
    if (tt + 4 < 32) b3 = *(const half8*)(bp + ((tt + 4) * 64 + lane) * 8);
#pragma unroll
    for (int r = 0; r < 16; r++) mx[r] = fmaxf(mx[r], dp[r]);
    dp = d;
  }
#pragma unroll
  for (int r = 0; r < 16; r++) mx[r] = fmaxf(mx[r], dp[r]);

  // reduce across 32 columns (xor masks <=16 stay within each 32-half)
#pragma unroll
  for (int m = 1; m <= 16; m <<= 1) {
#pragma unroll
    for (int r = 0; r < 16; r++) mx[r] = fmaxf(mx[r], __shfl_xor(mx[r], m));
  }
  // lane col==r (one per half) publishes row max; addresses all distinct
#pragma unroll
  for (int r = 0; r < 16; r++) {
    if (col == r) {
      unsigned row = (r & 3) + 8 * (r >> 2) + 4 * half;
      atomicMax(&qmax[qbase + row], okey(mx[r]));
    }
  }
}

// ---------------------------------------------------------------------------
// VQ pass 2: barrier-free pipelined re-scan; candidates >= global max - DELTA
// pushed to a per-wave LDS list (~1.4/query -> ~45/wave); fp64 rescore at end
// (fma chain/key/tie-break identical to all passing rounds).
__global__ __launch_bounds__(256, 3) void k_vq2(
    const _Float16* __restrict__ q16, const _Float16* __restrict__ cbf,
    const unsigned* __restrict__ qmax, const double* __restrict__ q64,
    const float* __restrict__ cbk, const double* __restrict__ cchalf,
    unsigned long long* __restrict__ keys) {
  __shared__ unsigned wlist[4][WCAP];  // 8 KB
  __shared__ int wcnt[4];
  int t = threadIdx.x;
  int w = t >> 6, lane = t & 63;
  int half = lane >> 5, col = lane & 31;
  if (lane == 0) wcnt[w] = 0;   // per-wave, no block barrier needed
  int qg = blockIdx.x >> 3;
  int cq = blockIdx.x & 7;
  int qbase = qg * 128 + w * 32;
  int cbase = cq * 1024;
  const _Float16* bp = cbf + (size_t)cq * 32 * 64 * 8;

  half8 a = *(const half8*)(q16 + (size_t)(qbase + col) * 16 + half * 8);
  f32x16 z = {0.f, 0.f, 0.f, 0.f, 0.f, 0.f, 0.f, 0.f,
              0.f, 0.f, 0.f, 0.f, 0.f, 0.f, 0.f, 0.f};

  float thr[16];
#pragma unroll
  for (int r = 0; r < 16; r++) {
    unsigned row = (r & 3) + 8 * (r >> 2) + 4 * half;
    thr[r] = unokey(qmax[qbase + row]) - DELTA;
  }

  half8 b0 = *(const half8*)(bp + (0 * 64 + lane) * 8);
  half8 b1 = *(const half8*)(bp + (1 * 64 + lane) * 8);
  half8 b2 = *(const half8*)(bp + (2 * 64 + lane) * 8);
  half8 b3 = *(const half8*)(bp + (3 * 64 + lane) * 8);

#define CONSUME(dv, ttv)                                                      \
  {                                                                           \
    _Pragma("unroll") for (int r = 0; r < 16; r++) {                          \
      if (dv[r] >= thr[r]) {                                                  \
        int slot = atomicAdd(&wcnt[w], 1);                                    \
        unsigned row = (r & 3) + 8 * (r >> 2) + 4 * half;                     \
        unsigned enc = ((unsigned)(qbase + row) << 13) |                      \
                       (unsigned)(cbase + (ttv)*32 + col);                    \
        if (slot < WCAP) wlist[w][slot] = enc;                                \
      }                                                                       \
    }                                                                         \
  }

  f32x16 dp = __builtin_amdgcn_mfma_f32_32x32x16_f16(a, b0, z, 0, 0, 0);
  b0 = b1; b1 = b2; b2 = b3;
  b3 = *(const half8*)(bp + (4 * 64 + lane) * 8);

#pragma unroll 4
  for (int tt = 1; tt < 32; tt++) {
    f32x16 d = __builtin_amdgcn_mfma_f32_32x32x16_f16(a, b0, z, 0, 0, 0);
    b0 = b1; b1 = b2; b2 = b3;
    if (tt + 4 < 32) b3 = *(const half8*)(bp + ((tt + 4) * 64 + lane) * 8);
    CONSUME(dp, tt - 1);
    dp = d;
  }
  CONSUME(dp, 31);
#undef CONSUME

  // rescore this wave's candidates exactly in fp64 (chain matches passing)
  int n = wcnt[w];
  if (n > WCAP) n = WCAP;
  for (int i = lane; i < n; i += 64) {
    unsigned e = wlist[w][i];
    int q = e >> 13, c = e & 8191;
    const double* qp = q64 + (size_t)q * 12;
    const float* cp = cbk + c * 12;
    double s = 0.0;
#pragma unroll
    for (int dd = 0; dd < 12; dd++) s = fma(qp[dd], (double)cp[dd], s);
    unsigned long long ek =
        (unsigned long long)((s - cchalf[c] + 2.0) * SCALE46);
    atomicMax(&keys[q], (ek << 16) | (unsigned)(8191 - c));
  }
}

// ---------------------------------------------------------------------------
// k_pre: decode ALL 8192 codebook rows once -> decoded[8192][64].
// Thread = (code, p2, kh): 65536 threads, grid 256. Weights in LDS. fp32 fma
// chains identical to the passing k_dec -> bit-identical rec values.
__global__ __launch_bounds__(256) void k_pre(
    const float* __restrict__ cbk, const float* __restrict__ d1r,
    const float* __restrict__ d2r, const float* __restrict__ d3r,
    const float* __restrict__ d1b, const float* __restrict__ d2b,
    const float* __restrict__ d3b, float* __restrict__ decoded) {
  __shared__ float w1s[1536], w2s[2048], w3s[64];
  __shared__ float b1s[32], b2s_[16];
  int t = threadIdx.x;
  for (int i = t; i < 1536; i += 256) w1s[i] = d1r[i];
  for (int i = t; i < 2048; i += 256) w2s[i] = d2r[i];
  if (t < 64) w3s[t] = d3r[t];
  else if (t >= 64 && t < 96) b1s[t - 64] = d1b[t - 64];
  else if (t >= 96 && t < 112) b2s_[t - 96] = d2b[t - 96];
  __syncthreads();

  int code = blockIdx.x * 32 + (t & 31);
  int p2 = (t >> 5) & 3;
  int kh = t >> 7;
  const float* cp = cbk + code * 12;
  float4 q0 = *(const float4*)(cp);
  float4 q1 = *(const float4*)(cp + 4);
  float4 q2 = *(const float4*)(cp + 8);

  const float* d1p = w1s + p2 * 384;
  float y1[32];
#pragma unroll
  for (int o = 0; o < 32; o++) {
    const float* wp = d1p + o * 12;
    float s = b1s[o];
    s = fmaf(q0.x, wp[0], s); s = fmaf(q0.y, wp[1], s);
    s = fmaf(q0.z, wp[2], s); s = fmaf(q0.w, wp[3], s);
    s = fmaf(q1.x, wp[4], s); s = fmaf(q1.y, wp[5], s);
    s = fmaf(q1.z, wp[6], s); s = fmaf(q1.w, wp[7], s);
    s = fmaf(q2.x, wp[8], s); s = fmaf(q2.y, wp[9], s);
    s = fmaf(q2.z, wp[10], s); s = fmaf(q2.w, wp[11], s);
    y1[o] = relu(s);
  }

  float d3bias = d3b[0];
#pragma unroll
  for (int kk2 = 0; kk2 < 2; kk2++) {
    int k = kh * 2 + kk2;
    const float* d2k = w2s + k * 512;
    float y2[16];
#pragma unroll
    for (int o = 0; o < 16; o++) {
      const float* wp = d2k + o * 32;
      float s = b2s_[o];
#pragma unroll
      for (int c = 0; c < 32; c += 4) {
        s = fmaf(y1[c + 0], wp[c + 0], s); s = fmaf(y1[c + 1], wp[c + 1], s);
        s = fmaf(y1[c + 2], wp[c + 2], s); s = fmaf(y1[c + 3], wp[c + 3], s);
      }
      y2[o] = relu(s);
    }
    float ov[4];
#pragma unroll
    for (int kk = 0; kk < 4; kk++) {
      const float* wp = w3s + kk * 16;
      float s = d3bias;
#pragma unroll
      for (int g = 0; g < 16; g += 4) {
        s = fmaf(y2[g + 0], wp[g + 0], s); s = fmaf(y2[g + 1], wp[g + 1], s);
        s = fmaf(y2[g + 2], wp[g + 2], s); s = fmaf(y2[g + 3], wp[g + 3], s);
      }
      ov[kk] = s;
    }
    *reinterpret_cast<float4*>(decoded + (size_t)code * 64 + p2 * 16 + k * 4) =
        make_float4(ov[0], ov[1], ov[2], ov[3]);
  }
}

// ---------------------------------------------------------------------------
// k_gather: rec[win] = decoded[key[win]]; quant_out from codebook.
__global__ __launch_bounds__(256) void k_gather(
    const unsigned long long* __restrict__ keys,
    const float* __restrict__ decoded, const float* __restrict__ cbk,
    float* __restrict__ quant_out, float* __restrict__ rec) {
  int g = blockIdx.x * 256 + threadIdx.x;  // grid 2048 -> 524288
  int win = g >> 4, i = g & 15;
  int gidx = 8191 - (int)(keys[win] & 0xFFFFull);
  float4 v = ((const float4*)(decoded + (size_t)gidx * 64))[i];
  ((float4*)(rec + (size_t)win * 64))[i] = v;
  if (i < 12) {
    int n = win >> 4, l = win & 15;
    quant_out[n * 192 + i * 16 + l] = cbk[gidx * 12 + i];
  }
}

// ---------------------------------------------------------------------------
extern "C" void kernel_launch(void* const* d_in, const int* in_sizes, int n_in,
                              void* d_out, int out_size, void* d_ws,
                              size_t ws_size, hipStream_t stream) {
  const float* x  = (const float*)d_in[0];
  const float* w1 = (const float*)d_in[1];
  const float* b1 = (const float*)d_in[2];
  const float* w2 = (const float*)d_in[3];
  const float* b2 = (const float*)d_in[4];
  const float* w3 = (const float*)d_in[5];
  const float* b3 = (const float*)d_in[6];
  int cb_idx = (in_sizes[13] == 98304) ? 13 : 7;
  int dbase = (cb_idx == 13) ? 7 : 8;
  const float* cbk = (const float*)d_in[cb_idx];
  const float* d1w = (const float*)d_in[dbase + 0];
  const float* d1b = (const float*)d_in[dbase + 1];
  const float* d2w = (const float*)d_in[dbase + 2];
  const float* d2b = (const float*)d_in[dbase + 3];
  const float* d3w = (const float*)d_in[dbase + 4];
  const float* d3b = (const float*)d_in[dbase + 5];

  float* out = (float*)d_out;
  float* rec = out;                 // (2048,1,1024)
  float* cont_out = out + 2097152;  // (2048,12,16)
  float* quant_out = out + 2490368; // (2048,12,16)

  char* wsb = (char*)d_ws;
  double* q64 = (double*)(wsb + WSB_Q64);
  float* decoded = (float*)(wsb + WSB_Q64);  // overlap: q64 dead after k_vq2
  unsigned* qmax = (unsigned*)(wsb + WSB_QZ);
  unsigned long long* keys = (unsigned long long*)(wsb + WSB_KEYS);
  double* cch = (double*)(wsb + WSB_CCH);
  float* d1r = (float*)(wsb + WSB_D1R);
  float* d2r = (float*)(wsb + WSB_D2R);
  float* d3r = (float*)(wsb + WSB_D3R);
  _Float16* cb16 = (_Float16*)(wsb + WSB_CB16);
  _Float16* q16 = (_Float16*)(wsb + WSB_Q16);

  k_enc<<<256, 512, 0, stream>>>(x, w1, b1, w2, b2, w3, b3, cbk, d1w, d2w,
                                 d3w, cont_out, q64, q16, qmax, cch, cb16,
                                 d1r, d2r, d3r);
  k_vq1<<<2048, 256, 0, stream>>>(q16, cb16, qmax, keys);
  k_vq2<<<2048, 256, 0, stream>>>(q16, cb16, qmax, q64, cbk, cch, keys);
  k_pre<<<256, 256, 0, stream>>>(cbk, d1r, d2r, d3r, d1b, d2b, d3b, decoded);
  k_gather<<<2048, 256, 0, stream>>>(keys, decoded, cbk, quant_out, rec);
}